// Round 4
// baseline (3007.313 us; speedup 1.0000x reference)
//
#include <hip/hip_runtime.h>
#include <cstdint>
#include <cstddef>

// DeltaNetMolecular R4: barrier-free fused edge kernel. All per-chunk data is
// wave-private (gathers land in C-layout registers, prefetched 1 chunk ahead;
// sH LDS rows are wave-owned) -> zero s_barrier in the 11-chunk loop, so the
// random B-side gathers stay in flight under a full chunk of MFMA/VALU work.
// Plus run-compressed graph pooling (batch sorted). Dense GEMMs: bf16x3 MFMA.

#define DEV __device__ __forceinline__

typedef __attribute__((ext_vector_type(8))) short bf16x8;
typedef __attribute__((ext_vector_type(4))) float f32x4;

DEV float siluf(float x) { return x / (1.f + __expf(-x)); }

DEV unsigned short f2bf(float f) {
  unsigned u = __float_as_uint(f);
  unsigned r = u + 0x7FFFu + ((u >> 16) & 1u);
  return (unsigned short)(r >> 16);
}
DEV float bf2f(unsigned short h) { return __uint_as_float(((unsigned)h) << 16); }

DEV f32x4 mfma16(bf16x8 a, bf16x8 b, f32x4 c) {
  return __builtin_amdgcn_mfma_f32_16x16x32_bf16(a, b, c, 0, 0, 0);
}

// ---------------------------------------------------------------- gather emb
__global__ __launch_bounds__(256) void k_gather(const int* __restrict__ atomids,
                                                const float* __restrict__ emb,
                                                float* __restrict__ feats_all, int N) {
  int idx = blockIdx.x * 256 + threadIdx.x;
  if (idx >= N * 128) return;
  int i = idx >> 7, j = idx & 127;
  feats_all[(size_t)i * 768 + j] = emb[atomids[i] * 128 + j];
}

// --------------------------------------------------- edge dist + dst histogram
__global__ __launch_bounds__(256) void k_edge_prep(const float* __restrict__ coords,
                                                   const int* __restrict__ ei, int E,
                                                   float* __restrict__ d_arr,
                                                   int* __restrict__ cnt) {
  int e = blockIdx.x * 256 + threadIdx.x;
  if (e >= E) return;
  int s = ei[e], t = ei[E + e];
  float dx = coords[3 * s + 0] - coords[3 * t + 0];
  float dy = coords[3 * s + 1] - coords[3 * t + 1];
  float dz = coords[3 * s + 2] - coords[3 * t + 2];
  d_arr[e] = dx * dx + dy * dy + dz * dz;
  atomicAdd(&cnt[t], 1);
}

// ------------------------------------------- single-block scan (N <= ~64K ok)
__global__ __launch_bounds__(1024) void k_scan(const int* __restrict__ cnt, int N,
                                               int* __restrict__ cursor,
                                               float* __restrict__ degf) {
  __shared__ int s[1024];
  __shared__ int carry;
  if (threadIdx.x == 0) carry = 0;
  __syncthreads();
  for (int base = 0; base < N; base += 1024) {
    int i = base + threadIdx.x;
    int v = (i < N) ? cnt[i] : 0;
    s[threadIdx.x] = v;
    __syncthreads();
    for (int off = 1; off < 1024; off <<= 1) {
      int add = (threadIdx.x >= off) ? s[threadIdx.x - off] : 0;
      __syncthreads();
      s[threadIdx.x] += add;
      __syncthreads();
    }
    if (i < N) {
      cursor[i] = s[threadIdx.x] - v + carry;
      degf[i] = fmaxf((float)v, 1.f);
    }
    __syncthreads();
    if (threadIdx.x == 0) carry += s[1023];
    __syncthreads();
  }
}

// ------------------------------------------------------- scatter sorted edges
__global__ __launch_bounds__(256) void k_scatter(const int* __restrict__ ei, int E,
                                                 const float* __restrict__ d_arr,
                                                 int* __restrict__ cursor,
                                                 int* __restrict__ ssrc,
                                                 int* __restrict__ sdst,
                                                 float* __restrict__ sd) {
  int e = blockIdx.x * 256 + threadIdx.x;
  if (e >= E) return;
  int s = ei[e], t = ei[E + e];
  int p = atomicAdd(&cursor[t], 1);
  ssrc[p] = s;
  sdst[p] = t;
  sd[p] = d_arr[e];
}

// ----------------------------------------------------- weight prepack (hi/lo)
__global__ __launch_bounds__(256) void k_prepack(
    const float* __restrict__ W, size_t wStride, int ldw,
    int K, int Kpad, int Ncols, int Npad,
    unsigned short* __restrict__ hi, unsigned short* __restrict__ lo, size_t oStride) {
  int idx = blockIdx.x * 256 + threadIdx.x;
  int total = Npad * Kpad;
  if (idx >= total) return;
  W += blockIdx.y * wStride;
  hi += blockIdx.y * oStride;
  lo += blockIdx.y * oStride;
  int n = idx / Kpad, k = idx - n * Kpad;
  float v = (n < Ncols && k < K) ? W[(size_t)k * ldw + n] : 0.f;
  unsigned short h = f2bf(v);
  hi[idx] = h;
  lo[idx] = f2bf(v - bf2f(h));
}

// ------------------------------------------- generic bf16x3 MFMA GEMM (M=128)
__global__ __launch_bounds__(256) void gemm_mfma(
    const float* __restrict__ A, int lda,
    const unsigned short* __restrict__ Bhi, const unsigned short* __restrict__ Blo,
    int Kpad, const float* __restrict__ bias,
    float* __restrict__ C, int ldc,
    int M, int Ncols, int K, int actOut, int actA) {
  const int t = threadIdx.x;
  const int wave = t >> 6, lane = t & 63;
  const int nl = lane & 15, quad = lane >> 4;
  const int bm = blockIdx.x * 128 + wave * 32;
  const int bn = blockIdx.y * 64;
  f32x4 zero = {0.f, 0.f, 0.f, 0.f};
  f32x4 acc[2][4] = {{zero, zero, zero, zero}, {zero, zero, zero, zero}};
  for (int kb = 0; kb < K; kb += 32) {
    bf16x8 ah[2], al[2];
#pragma unroll
    for (int h = 0; h < 2; ++h) {
      int row = bm + h * 16 + nl;
      float av[8];
      if (row < M) {
        const float* ap = A + (size_t)row * lda + kb + quad * 8;
        f32x4 v0 = *(const f32x4*)ap;
        f32x4 v1 = *(const f32x4*)(ap + 4);
        av[0] = v0.x; av[1] = v0.y; av[2] = v0.z; av[3] = v0.w;
        av[4] = v1.x; av[5] = v1.y; av[6] = v1.z; av[7] = v1.w;
        if (actA) {
#pragma unroll
          for (int j = 0; j < 8; ++j) av[j] = siluf(av[j]);
        }
      } else {
#pragma unroll
        for (int j = 0; j < 8; ++j) av[j] = 0.f;
      }
#pragma unroll
      for (int j = 0; j < 8; ++j) {
        unsigned short hh = f2bf(av[j]);
        ah[h][j] = (short)hh;
        al[h][j] = (short)f2bf(av[j] - bf2f(hh));
      }
    }
#pragma unroll
    for (int tn = 0; tn < 4; ++tn) {
      size_t boff = (size_t)(bn + tn * 16 + nl) * Kpad + kb + quad * 8;
      bf16x8 bh = *(const bf16x8*)(Bhi + boff);
      bf16x8 bl = *(const bf16x8*)(Blo + boff);
#pragma unroll
      for (int h = 0; h < 2; ++h) {
        acc[h][tn] = mfma16(ah[h], bh, acc[h][tn]);
        acc[h][tn] = mfma16(ah[h], bl, acc[h][tn]);
        acc[h][tn] = mfma16(al[h], bh, acc[h][tn]);
      }
    }
  }
#pragma unroll
  for (int h = 0; h < 2; ++h) {
#pragma unroll
    for (int tn = 0; tn < 4; ++tn) {
      int c = bn + tn * 16 + nl;
      if (c >= Ncols) continue;
      float bv = bias ? bias[c] : 0.f;
#pragma unroll
      for (int r = 0; r < 4; ++r) {
        int rr = bm + h * 16 + quad * 4 + r;
        if (rr >= M) continue;
        float v = acc[h][tn][r] + bv;
        if (actOut) v = siluf(v);
        C[(size_t)rr * ldc + c] = v;
      }
    }
  }
}

// --------------------------- fused edge kernel (wave-private, barrier-free)
__global__ __launch_bounds__(256) void k_edge_mfma(
    const float* __restrict__ Ab, const float* __restrict__ Bb,  // [N,644]
    const int* __restrict__ ssrc, const int* __restrict__ sdst,
    const float* __restrict__ sd_g, int E,
    const unsigned short* __restrict__ WeaThi, const unsigned short* __restrict__ WeaTlo,
    const float* __restrict__ Wea64,
    const unsigned short* __restrict__ W2Thi, const unsigned short* __restrict__ W2Tlo,
    const float* __restrict__ b2v,
    const float* __restrict__ eng, const float* __restrict__ enb,
    float* __restrict__ msum) {
  __shared__ float sH[64 * 68];   // wave-private rows [wave*16, wave*16+16)
  __shared__ float sM[64 * 33];   // LN'd messages (separate: no alias w/ sH)
  __shared__ float sDs[64];
  __shared__ int sSrcS[64], sDstS[64];

  const int t = threadIdx.x;
  const int wave = t >> 6, lane = t & 63;
  const int nl = lane & 15, quad = lane >> 4;
  const int e0 = blockIdx.x * 64;

  // wave-private edge meta (lanes>=16 read after same-wave lgkm ordering)
  if (lane < 16) {
    int el = wave * 16 + lane;
    int e = e0 + el;
    int ec = (e < E) ? e : (E - 1);
    sSrcS[el] = ssrc[ec];
    sDstS[el] = sdst[ec];
    sDs[el] = sd_g[ec];
  }

  // ea A-frags (register-resident), edge m = wave*16+nl
  bf16x8 eaHi[2], eaLo[2];
  {
    float d = sDs[wave * 16 + nl];
#pragma unroll
    for (int ks = 0; ks < 2; ++ks) {
#pragma unroll
      for (int j = 0; j < 8; ++j) {
        int k = ks * 32 + quad * 8 + j;
        float arg = d * exp2f(-(float)(k & 31));
        float v = (k < 32) ? sinf(arg) : cosf(arg);
        unsigned short h = f2bf(v);
        eaHi[ks][j] = (short)h;
        eaLo[ks][j] = (short)f2bf(v - bf2f(h));
      }
    }
  }

  // per-lane edge base pointers (C-layout rows quad*4+r), col base nl
  const float* aP[4];
  const float* bP[4];
  float dv[4];
#pragma unroll
  for (int r = 0; r < 4; ++r) {
    int el = wave * 16 + quad * 4 + r;
    aP[r] = Ab + (size_t)sDstS[el] * 644 + nl;
    bP[r] = Bb + (size_t)sSrcS[el] * 644 + nl;
    dv[r] = sDs[el];
  }

  f32x4 zero = {0.f, 0.f, 0.f, 0.f};
  f32x4 macc[2] = {zero, zero};

  // prefetch chunk 0 B-gathers (random src: the high-latency side)
  float nB[4][4];
#pragma unroll
  for (int tn = 0; tn < 4; ++tn)
#pragma unroll
    for (int r = 0; r < 4; ++r) nB[tn][r] = bP[r][tn * 16];

  for (int c = 0; c < 11; ++c) {
    const int jb = c * 64;
    // GEMM1: ea[16x64] @ Wea_chunk -> acc1 (C-layout)
    f32x4 acc1[4] = {zero, zero, zero, zero};
#pragma unroll
    for (int tn = 0; tn < 4; ++tn) {
      size_t base = (size_t)(jb + tn * 16 + nl) * 64 + quad * 8;
#pragma unroll
      for (int ks = 0; ks < 2; ++ks) {
        bf16x8 bh = *(const bf16x8*)(WeaThi + base + ks * 32);
        bf16x8 bl = *(const bf16x8*)(WeaTlo + base + ks * 32);
        acc1[tn] = mfma16(eaHi[ks], bh, acc1[tn]);
        acc1[tn] = mfma16(eaHi[ks], bl, acc1[tn]);
        acc1[tn] = mfma16(eaLo[ks], bh, acc1[tn]);
      }
    }
    // z = acc1 + A[dst] (L1-hot, inline) + B[src] (prefetched) + d*w64; silu
#pragma unroll
    for (int tn = 0; tn < 4; ++tn) {
      int col = jb + tn * 16 + nl;
      float w64 = (col < 642) ? Wea64[col] : 0.f;
#pragma unroll
      for (int r = 0; r < 4; ++r) {
        int el = wave * 16 + quad * 4 + r;
        float z = acc1[tn][r] + aP[r][jb + tn * 16] + nB[tn][r] + dv[r] * w64;
        sH[el * 68 + tn * 16 + nl] = siluf(z);
      }
    }
    // prefetch next chunk's B-gathers (full chunk of latency cover, no barrier)
    if (c + 1 < 11) {
      const int off = (c + 1) * 64;
#pragma unroll
      for (int tn = 0; tn < 4; ++tn)
#pragma unroll
        for (int r = 0; r < 4; ++r) nB[tn][r] = bP[r][off + tn * 16];
    }
    // GEMM2: h_chunk[16x64] @ W2_chunk[64x32] (sH rows wave-private)
#pragma unroll
    for (int ks = 0; ks < 2; ++ks) {
      const float* hp = &sH[(wave * 16 + nl) * 68 + ks * 32 + quad * 8];
      f32x4 h0 = *(const f32x4*)hp;
      f32x4 h1 = *(const f32x4*)(hp + 4);
      float hv[8] = {h0.x, h0.y, h0.z, h0.w, h1.x, h1.y, h1.z, h1.w};
      bf16x8 ah, al;
#pragma unroll
      for (int j = 0; j < 8; ++j) {
        unsigned short hh = f2bf(hv[j]);
        ah[j] = (short)hh;
        al[j] = (short)f2bf(hv[j] - bf2f(hh));
      }
#pragma unroll
      for (int tn = 0; tn < 2; ++tn) {
        size_t base = (size_t)(tn * 16 + nl) * 704 + jb + ks * 32 + quad * 8;
        bf16x8 bh = *(const bf16x8*)(W2Thi + base);
        bf16x8 bl = *(const bf16x8*)(W2Tlo + base);
        macc[tn] = mfma16(ah, bh, macc[tn]);
        macc[tn] = mfma16(ah, bl, macc[tn]);
        macc[tn] = mfma16(al, bh, macc[tn]);
      }
    }
  }

  // epilogue: bias + silu + LN(32) via width-16 shuffles -> sM (own rows)
  float g0 = eng[nl], g1v = eng[16 + nl], bb0 = enb[nl], bb1 = enb[16 + nl];
  float bi0 = b2v[nl], bi1 = b2v[16 + nl];
#pragma unroll
  for (int r = 0; r < 4; ++r) {
    float v0 = siluf(macc[0][r] + bi0);
    float v1 = siluf(macc[1][r] + bi1);
    float s = v0 + v1;
    float ss = v0 * v0 + v1 * v1;
#pragma unroll
    for (int m = 1; m < 16; m <<= 1) {
      s += __shfl_xor(s, m, 16);
      ss += __shfl_xor(ss, m, 16);
    }
    float mu = s * (1.f / 32.f);
    float var = ss * (1.f / 32.f) - mu * mu;
    float rs = rsqrtf(var + 1e-5f);
    int eb = wave * 16 + quad * 4 + r;
    sM[eb * 33 + nl] = (v0 - mu) * rs * g0 + bb0;
    sM[eb * 33 + 16 + nl] = (v1 - mu) * rs * g1v + bb1;
  }
  __syncthreads();  // the ONLY barrier: sM/sDstS now visible to all waves
  {
    int col = t & 31, seg = t >> 5;
    float acc = 0.f;
    int cur = -1;
#pragma unroll
    for (int i = 0; i < 8; ++i) {
      int e = seg * 8 + i;
      int dn = (e0 + e < E) ? sDstS[e] : -1;
      if (dn != cur) {
        if (cur >= 0) atomicAdd(&msum[(size_t)cur * 32 + col], acc);
        acc = 0.f;
        cur = dn;
      }
      if (dn >= 0) acc += sM[e * 33 + col];
    }
    if (cur >= 0) atomicAdd(&msum[(size_t)cur * 32 + col], acc);
  }
}

// --------------------------------------------- node-side LN + concat builder
__global__ __launch_bounds__(256) void k_node_ln(
    const float* __restrict__ msum, const float* __restrict__ deg,
    const float* __restrict__ featsAll, int k,
    const float* __restrict__ n1g, const float* __restrict__ n1b,
    const float* __restrict__ eng, const float* __restrict__ enb,
    float* __restrict__ hcat, int N) {
  int node = blockIdx.x * 4 + (threadIdx.x >> 6);
  int lane = threadIdx.x & 63;
  if (node >= N) return;
  const float* fr = featsAll + (size_t)node * 768 + k * 128;
  float x0 = fr[lane], x1 = fr[64 + lane];
  float s = x0 + x1;
#pragma unroll
  for (int m = 1; m < 64; m <<= 1) s += __shfl_xor(s, m, 64);
  float mu = s * (1.f / 128.f);
  float d0 = x0 - mu, d1 = x1 - mu;
  float v = d0 * d0 + d1 * d1;
#pragma unroll
  for (int m = 1; m < 64; m <<= 1) v += __shfl_xor(v, m, 64);
  float rstd = rsqrtf(v * (1.f / 128.f) + 1e-5f);
  float* hr = hcat + (size_t)node * 160;
  hr[lane] = d0 * rstd * n1g[lane] + n1b[lane];
  hr[64 + lane] = d1 * rstd * n1g[64 + lane] + n1b[64 + lane];
  float dg = deg[node];
  int col = lane & 31;
  float y = msum[(size_t)node * 32 + col] / dg;
  float sy = y;
#pragma unroll
  for (int m = 1; m < 32; m <<= 1) sy += __shfl_xor(sy, m, 32);
  float mu2 = sy * (1.f / 32.f);
  float dy = y - mu2;
  float vy = dy * dy;
#pragma unroll
  for (int m = 1; m < 32; m <<= 1) vy += __shfl_xor(vy, m, 32);
  float rstd2 = rsqrtf(vy * (1.f / 32.f) + 1e-5f);
  if (lane < 32) hr[128 + col] = dy * rstd2 * eng[col] + enb[col];
}

// ------------------------------------------------ node residual + final LN
__global__ __launch_bounds__(256) void k_node_resid(
    const float* __restrict__ t2, float* __restrict__ featsAll, int k,
    const float* __restrict__ n2g, const float* __restrict__ n2b, int N) {
  int node = blockIdx.x * 4 + (threadIdx.x >> 6);
  int lane = threadIdx.x & 63;
  if (node >= N) return;
  const float* tr = t2 + (size_t)node * 128;
  float x0 = tr[lane], x1 = tr[64 + lane];
  float s = x0 + x1;
#pragma unroll
  for (int m = 1; m < 64; m <<= 1) s += __shfl_xor(s, m, 64);
  float mu = s * (1.f / 128.f);
  float d0 = x0 - mu, d1 = x1 - mu;
  float v = d0 * d0 + d1 * d1;
#pragma unroll
  for (int m = 1; m < 64; m <<= 1) v += __shfl_xor(v, m, 64);
  float rstd = rsqrtf(v * (1.f / 128.f) + 1e-5f);
  const float* fk = featsAll + (size_t)node * 768 + k * 128;
  float* fo = featsAll + (size_t)node * 768 + (k + 1) * 128;
  fo[lane] = fk[lane] + d0 * rstd * n2g[lane] + n2b[lane];
  fo[64 + lane] = fk[64 + lane] + d1 * rstd * n2g[64 + lane] + n2b[64 + lane];
}

// ------------------------------------- graph pooling (batch sorted -> runs)
__global__ __launch_bounds__(256) void k_pool2(const float* __restrict__ f,
                                               const int* __restrict__ batch,
                                               float* __restrict__ gsum,
                                               float* __restrict__ gcnt, int N) {
  int n0 = blockIdx.x * 64;
  int col = threadIdx.x;
  float acc = 0.f;
  int cur = -1;
  for (int i = 0; i < 64; ++i) {
    int n = n0 + i;
    if (n >= N) break;
    int b = batch[n];
    if (b != cur) {
      if (cur >= 0) atomicAdd(&gsum[cur * 256 + col], acc);
      acc = 0.f;
      cur = b;
    }
    acc += f[(size_t)n * 256 + col];
  }
  if (cur >= 0) atomicAdd(&gsum[cur * 256 + col], acc);
  if (threadIdx.x == 0) {
    int cnt = 0;
    cur = -1;
    for (int i = 0; i < 64; ++i) {
      int n = n0 + i;
      if (n >= N) break;
      int b = batch[n];
      if (b != cur) {
        if (cur >= 0) atomicAdd(&gcnt[cur], (float)cnt);
        cnt = 0;
        cur = b;
      }
      cnt++;
    }
    if (cur >= 0) atomicAdd(&gcnt[cur], (float)cnt);
  }
}

__global__ void k_gdiv(float* gsum, const float* gcnt) {
  int b = blockIdx.x, j = threadIdx.x;
  gsum[b * 256 + j] /= fmaxf(gcnt[b], 1.f);
}

__global__ void k_gout(const float* __restrict__ g2, const float* __restrict__ gW2,
                       const float* __restrict__ gb2, float* __restrict__ out) {
  int b = threadIdx.x;
  if (b >= 64) return;
  float s = gb2[0];
  for (int j = 0; j < 256; ++j) s += g2[b * 256 + j] * gW2[j];
  out[b] = s;
}

// ------------------------------------------------------------------- launch
extern "C" void kernel_launch(void* const* d_in, const int* in_sizes, int n_in,
                              void* d_out, int out_size, void* d_ws, size_t ws_size,
                              hipStream_t stream) {
  const float* coords = (const float*)d_in[0];
  const int* atomids = (const int*)d_in[1];
  const int* ei = (const int*)d_in[2];
  const int* batch = (const int*)d_in[3];
  const float* emb = (const float*)d_in[5];
  const float* keW1 = (const float*)d_in[6];
  const float* keb1 = (const float*)d_in[7];
  const float* keW2 = (const float*)d_in[8];
  const float* keb2 = (const float*)d_in[9];
  const float* keng = (const float*)d_in[10];
  const float* kenb = (const float*)d_in[11];
  const float* kn1g = (const float*)d_in[12];
  const float* kn1b = (const float*)d_in[13];
  const float* knW1 = (const float*)d_in[14];
  const float* knb1 = (const float*)d_in[15];
  const float* knW2 = (const float*)d_in[16];
  const float* knb2 = (const float*)d_in[17];
  const float* kn2g = (const float*)d_in[18];
  const float* kn2b = (const float*)d_in[19];
  const float* fW0 = (const float*)d_in[20];
  const float* fb0 = (const float*)d_in[21];
  const float* fW1 = (const float*)d_in[22];
  const float* fb1 = (const float*)d_in[23];
  const float* fW2 = (const float*)d_in[24];
  const float* fb2 = (const float*)d_in[25];
  const float* gW0 = (const float*)d_in[26];
  const float* gb0 = (const float*)d_in[27];
  const float* gW1 = (const float*)d_in[28];
  const float* gb1 = (const float*)d_in[29];
  const float* gW2 = (const float*)d_in[30];
  const float* gb2 = (const float*)d_in[31];

  const int N = in_sizes[0] / 3;
  const int E = in_sizes[2] / 2;

  size_t off = 0;
  auto alloc = [&](size_t n) {
    float* p = (float*)d_ws + off;
    off += (n + 63) & ~(size_t)63;
    return p;
  };
  float* feats_all = alloc((size_t)N * 768);
  float* d_arr = alloc(E);
  float* degf = alloc(N);
  float* msum = alloc((size_t)N * 32);
  float* Abuf = alloc((size_t)N * 644);
  float* Bbuf = alloc((size_t)N * 644);
  float* gsum = alloc(64 * 256);
  float* gcnt = alloc(64);
  float* g1 = alloc(64 * 256);
  float* g2 = alloc(64 * 256);
  int* cnt = (int*)alloc(N);
  int* cursor = (int*)alloc(N);
  int* ssrc = (int*)alloc(E);
  int* sdst = (int*)alloc(E);
  float* sd = alloc(E);
  float* hcat = Abuf;                  // N x 160
  float* t1 = Abuf + (size_t)N * 160;  // N x 256
  float* t2 = Abuf + (size_t)N * 416;  // N x 128
  float* f1 = Bbuf;                    // N x 256
  float* f2 = Bbuf + (size_t)N * 256;  // N x 256

  unsigned short* ubase = (unsigned short*)(alloc(0));
  size_t uoff = 0;
  auto ualloc = [&](size_t n) {
    unsigned short* p = ubase + uoff;
    uoff += (n + 63) & ~(size_t)63;
    return p;
  };
  const size_t sDst_ = 704 * 128, sSrc_ = 704 * 128, sEa_ = 704 * 64;
  const size_t sW2_ = 32 * 704, sN1_ = 256 * 160, sN2_ = 128 * 256;
  unsigned short* PdstH = ualloc(5 * sDst_); unsigned short* PdstL = ualloc(5 * sDst_);
  unsigned short* PsrcH = ualloc(5 * sSrc_); unsigned short* PsrcL = ualloc(5 * sSrc_);
  unsigned short* PeaH = ualloc(5 * sEa_);   unsigned short* PeaL = ualloc(5 * sEa_);
  unsigned short* PW2H = ualloc(5 * sW2_);   unsigned short* PW2L = ualloc(5 * sW2_);
  unsigned short* Pn1H = ualloc(5 * sN1_);   unsigned short* Pn1L = ualloc(5 * sN1_);
  unsigned short* Pn2H = ualloc(5 * sN2_);   unsigned short* Pn2L = ualloc(5 * sN2_);
  unsigned short* Pf0H = ualloc(256 * 768);  unsigned short* Pf0L = ualloc(256 * 768);
  unsigned short* Pf1H = ualloc(256 * 256);  unsigned short* Pf1L = ualloc(256 * 256);
  unsigned short* Pf2H = ualloc(256 * 256);  unsigned short* Pf2L = ualloc(256 * 256);
  unsigned short* Pg0H = ualloc(256 * 256);  unsigned short* Pg0L = ualloc(256 * 256);
  unsigned short* Pg1H = ualloc(256 * 256);  unsigned short* Pg1L = ualloc(256 * 256);

  auto pp = [&](const float* W, size_t wStr, int ldw, int K, int Kpad, int Nc, int Npad,
                unsigned short* hi, unsigned short* lo, size_t oStr, int layers) {
    int total = Npad * Kpad;
    k_prepack<<<dim3((total + 255) / 256, layers), 256, 0, stream>>>(
        W, wStr, ldw, K, Kpad, Nc, Npad, hi, lo, oStr);
  };
  pp(keW1, (size_t)321 * 642, 642, 128, 128, 642, 704, PdstH, PdstL, sDst_, 5);
  pp(keW1 + 128 * 642, (size_t)321 * 642, 642, 128, 128, 642, 704, PsrcH, PsrcL, sSrc_, 5);
  pp(keW1 + 256 * 642, (size_t)321 * 642, 642, 64, 64, 642, 704, PeaH, PeaL, sEa_, 5);
  pp(keW2, (size_t)642 * 32, 32, 642, 704, 32, 32, PW2H, PW2L, sW2_, 5);
  pp(knW1, (size_t)160 * 256, 256, 160, 160, 256, 256, Pn1H, Pn1L, sN1_, 5);
  pp(knW2, (size_t)256 * 128, 128, 256, 256, 128, 128, Pn2H, Pn2L, sN2_, 5);
  pp(fW0, 0, 256, 768, 768, 256, 256, Pf0H, Pf0L, 0, 1);
  pp(fW1, 0, 256, 256, 256, 256, 256, Pf1H, Pf1L, 0, 1);
  pp(fW2, 0, 256, 256, 256, 256, 256, Pf2H, Pf2L, 0, 1);
  pp(gW0, 0, 256, 256, 256, 256, 256, Pg0H, Pg0L, 0, 1);
  pp(gW1, 0, 256, 256, 256, 256, 256, Pg1H, Pg1L, 0, 1);

  // ---- edge sort by dst (counting sort)
  k_gather<<<(N * 128 + 255) / 256, 256, 0, stream>>>(atomids, emb, feats_all, N);
  hipMemsetAsync(cnt, 0, (size_t)N * sizeof(int), stream);
  k_edge_prep<<<(E + 255) / 256, 256, 0, stream>>>(coords, ei, E, d_arr, cnt);
  k_scan<<<1, 1024, 0, stream>>>(cnt, N, cursor, degf);
  k_scatter<<<(E + 255) / 256, 256, 0, stream>>>(ei, E, d_arr, cursor, ssrc, sdst, sd);

  const int MT = (N + 127) / 128;
  for (int k = 0; k < 5; ++k) {
    gemm_mfma<<<dim3(MT, 11), 256, 0, stream>>>(
        feats_all + k * 128, 768, PdstH + k * sDst_, PdstL + k * sDst_, 128,
        keb1 + k * 642, Abuf, 644, N, 642, 128, 0, 0);
    gemm_mfma<<<dim3(MT, 11), 256, 0, stream>>>(
        feats_all + k * 128, 768, PsrcH + k * sSrc_, PsrcL + k * sSrc_, 128,
        nullptr, Bbuf, 644, N, 642, 128, 0, 0);
    hipMemsetAsync(msum, 0, (size_t)N * 32 * sizeof(float), stream);
    k_edge_mfma<<<(E + 63) / 64, 256, 0, stream>>>(
        Abuf, Bbuf, ssrc, sdst, sd, E,
        PeaH + k * sEa_, PeaL + k * sEa_,
        keW1 + (size_t)k * 321 * 642 + (size_t)320 * 642,
        PW2H + k * sW2_, PW2L + k * sW2_,
        keb2 + k * 32, keng + k * 32, kenb + k * 32, msum);
    k_node_ln<<<(N + 3) / 4, 256, 0, stream>>>(
        msum, degf, feats_all, k, kn1g + k * 128, kn1b + k * 128,
        keng + k * 32, kenb + k * 32, hcat, N);
    gemm_mfma<<<dim3(MT, 4), 256, 0, stream>>>(
        hcat, 160, Pn1H + k * sN1_, Pn1L + k * sN1_, 160,
        knb1 + k * 256, t1, 256, N, 256, 160, 1, 0);
    gemm_mfma<<<dim3(MT, 2), 256, 0, stream>>>(
        t1, 256, Pn2H + k * sN2_, Pn2L + k * sN2_, 256,
        knb2 + k * 128, t2, 128, N, 128, 256, 0, 0);
    k_node_resid<<<(N + 3) / 4, 256, 0, stream>>>(
        t2, feats_all, k, kn2g + k * 128, kn2b + k * 128, N);
  }

  gemm_mfma<<<dim3(MT, 4), 256, 0, stream>>>(
      feats_all, 768, Pf0H, Pf0L, 768, fb0, f1, 256, N, 256, 768, 1, 1);
  gemm_mfma<<<dim3(MT, 4), 256, 0, stream>>>(
      f1, 256, Pf1H, Pf1L, 256, fb1, f2, 256, N, 256, 256, 1, 0);
  gemm_mfma<<<dim3(MT, 4), 256, 0, stream>>>(
      f2, 256, Pf2H, Pf2L, 256, fb2, f1, 256, N, 256, 256, 1, 0);

  hipMemsetAsync(gsum, 0, 64 * 256 * sizeof(float), stream);
  hipMemsetAsync(gcnt, 0, 64 * sizeof(float), stream);
  k_pool2<<<(N + 63) / 64, 256, 0, stream>>>(f1, batch, gsum, gcnt, N);
  k_gdiv<<<64, 256, 0, stream>>>(gsum, gcnt);
  gemm_mfma<<<dim3(1, 4), 256, 0, stream>>>(
      gsum, 256, Pg0H, Pg0L, 256, gb0, g1, 256, 64, 256, 256, 1, 0);
  gemm_mfma<<<dim3(1, 4), 256, 0, stream>>>(
      g1, 256, Pg1H, Pg1L, 256, gb1, g2, 256, 64, 256, 256, 1, 0);
  k_gout<<<1, 64, 0, stream>>>(g2, gW2, gb2, (float*)d_out);
}

// Round 5
// 2877.456 us; speedup vs baseline: 1.0451x; 1.0451x over previous
//
#include <hip/hip_runtime.h>
#include <cstdint>
#include <cstddef>

// DeltaNetMolecular R5: edge kernel with wave-private cooperative staging
// (float4 gathers into wave-owned LDS, ZERO main-loop barriers) + all dense
// GEMM A-operands prepacked hi/lo bf16 (no per-kstep repack VALU).

#define DEV __device__ __forceinline__

typedef __attribute__((ext_vector_type(8))) short bf16x8;
typedef __attribute__((ext_vector_type(4))) float f32x4;

DEV float siluf(float x) { return x / (1.f + __expf(-x)); }

DEV unsigned short f2bf(float f) {
  unsigned u = __float_as_uint(f);
  unsigned r = u + 0x7FFFu + ((u >> 16) & 1u);
  return (unsigned short)(r >> 16);
}
DEV float bf2f(unsigned short h) { return __uint_as_float(((unsigned)h) << 16); }

DEV f32x4 mfma16(bf16x8 a, bf16x8 b, f32x4 c) {
  return __builtin_amdgcn_mfma_f32_16x16x32_bf16(a, b, c, 0, 0, 0);
}

// ------------------------------------------------- gather emb (+hi/lo copies)
__global__ __launch_bounds__(256) void k_gather(const int* __restrict__ atomids,
                                                const float* __restrict__ emb,
                                                float* __restrict__ feats_all,
                                                unsigned short* __restrict__ fH,
                                                unsigned short* __restrict__ fL, int N) {
  int idx = blockIdx.x * 256 + threadIdx.x;
  if (idx >= N * 128) return;
  int i = idx >> 7, j = idx & 127;
  float v = emb[atomids[i] * 128 + j];
  size_t o = (size_t)i * 768 + j;
  feats_all[o] = v;
  unsigned short h = f2bf(v);
  fH[o] = h;
  fL[o] = f2bf(v - bf2f(h));
}

// --------------------------------------------------- edge dist + dst histogram
__global__ __launch_bounds__(256) void k_edge_prep(const float* __restrict__ coords,
                                                   const int* __restrict__ ei, int E,
                                                   float* __restrict__ d_arr,
                                                   int* __restrict__ cnt) {
  int e = blockIdx.x * 256 + threadIdx.x;
  if (e >= E) return;
  int s = ei[e], t = ei[E + e];
  float dx = coords[3 * s + 0] - coords[3 * t + 0];
  float dy = coords[3 * s + 1] - coords[3 * t + 1];
  float dz = coords[3 * s + 2] - coords[3 * t + 2];
  d_arr[e] = dx * dx + dy * dy + dz * dz;
  atomicAdd(&cnt[t], 1);
}

// ------------------------------------------- single-block scan (N <= ~64K ok)
__global__ __launch_bounds__(1024) void k_scan(const int* __restrict__ cnt, int N,
                                               int* __restrict__ cursor,
                                               float* __restrict__ degf) {
  __shared__ int s[1024];
  __shared__ int carry;
  if (threadIdx.x == 0) carry = 0;
  __syncthreads();
  for (int base = 0; base < N; base += 1024) {
    int i = base + threadIdx.x;
    int v = (i < N) ? cnt[i] : 0;
    s[threadIdx.x] = v;
    __syncthreads();
    for (int off = 1; off < 1024; off <<= 1) {
      int add = (threadIdx.x >= off) ? s[threadIdx.x - off] : 0;
      __syncthreads();
      s[threadIdx.x] += add;
      __syncthreads();
    }
    if (i < N) {
      cursor[i] = s[threadIdx.x] - v + carry;
      degf[i] = fmaxf((float)v, 1.f);
    }
    __syncthreads();
    if (threadIdx.x == 0) carry += s[1023];
    __syncthreads();
  }
}

// ------------------------------------------------------- scatter sorted edges
__global__ __launch_bounds__(256) void k_scatter(const int* __restrict__ ei, int E,
                                                 const float* __restrict__ d_arr,
                                                 int* __restrict__ cursor,
                                                 int* __restrict__ ssrc,
                                                 int* __restrict__ sdst,
                                                 float* __restrict__ sd) {
  int e = blockIdx.x * 256 + threadIdx.x;
  if (e >= E) return;
  int s = ei[e], t = ei[E + e];
  int p = atomicAdd(&cursor[t], 1);
  ssrc[p] = s;
  sdst[p] = t;
  sd[p] = d_arr[e];
}

// ----------------------------------------------------- weight prepack (hi/lo)
__global__ __launch_bounds__(256) void k_prepack(
    const float* __restrict__ W, size_t wStride, int ldw,
    int K, int Kpad, int Ncols, int Npad,
    unsigned short* __restrict__ hi, unsigned short* __restrict__ lo, size_t oStride) {
  int idx = blockIdx.x * 256 + threadIdx.x;
  int total = Npad * Kpad;
  if (idx >= total) return;
  W += blockIdx.y * wStride;
  hi += blockIdx.y * oStride;
  lo += blockIdx.y * oStride;
  int n = idx / Kpad, k = idx - n * Kpad;
  float v = (n < Ncols && k < K) ? W[(size_t)k * ldw + n] : 0.f;
  unsigned short h = f2bf(v);
  hi[idx] = h;
  lo[idx] = f2bf(v - bf2f(h));
}

// ------------------- bf16x3 MFMA GEMM, A prepacked hi/lo bf16 (M=128/block)
__global__ __launch_bounds__(256) void gemm_bf(
    const unsigned short* __restrict__ AH, const unsigned short* __restrict__ AL, int lda,
    const unsigned short* __restrict__ BH, const unsigned short* __restrict__ BL, int ldb,
    const float* __restrict__ bias,
    float* __restrict__ C, int ldc,
    unsigned short* __restrict__ CH, unsigned short* __restrict__ CL, int ldch,
    int M, int Ncols, int K, int actOut, int actA) {
  const int t = threadIdx.x;
  const int wave = t >> 6, lane = t & 63;
  const int nl = lane & 15, quad = lane >> 4;
  const int bm = blockIdx.x * 128 + wave * 32;
  const int bn = blockIdx.y * 64;
  f32x4 zero = {0.f, 0.f, 0.f, 0.f};
  f32x4 acc[2][4] = {{zero, zero, zero, zero}, {zero, zero, zero, zero}};
  for (int kb = 0; kb < K; kb += 32) {
    bf16x8 ah[2], al[2];
#pragma unroll
    for (int h = 0; h < 2; ++h) {
      int row = bm + h * 16 + nl;
      if (row < M) {
        size_t o = (size_t)row * lda + kb + quad * 8;
        ah[h] = *(const bf16x8*)(AH + o);
        al[h] = *(const bf16x8*)(AL + o);
        if (actA) {
#pragma unroll
          for (int j = 0; j < 8; ++j) {
            float a = bf2f((unsigned short)ah[h][j]) + bf2f((unsigned short)al[h][j]);
            a = siluf(a);
            unsigned short hh = f2bf(a);
            ah[h][j] = (short)hh;
            al[h][j] = (short)f2bf(a - bf2f(hh));
          }
        }
      } else {
#pragma unroll
        for (int j = 0; j < 8; ++j) { ah[h][j] = 0; al[h][j] = 0; }
      }
    }
#pragma unroll
    for (int tn = 0; tn < 4; ++tn) {
      size_t boff = (size_t)(bn + tn * 16 + nl) * ldb + kb + quad * 8;
      bf16x8 bh = *(const bf16x8*)(BH + boff);
      bf16x8 bl = *(const bf16x8*)(BL + boff);
#pragma unroll
      for (int h = 0; h < 2; ++h) {
        acc[h][tn] = mfma16(ah[h], bh, acc[h][tn]);
        acc[h][tn] = mfma16(ah[h], bl, acc[h][tn]);
        acc[h][tn] = mfma16(al[h], bh, acc[h][tn]);
      }
    }
  }
#pragma unroll
  for (int h = 0; h < 2; ++h) {
#pragma unroll
    for (int tn = 0; tn < 4; ++tn) {
      int c = bn + tn * 16 + nl;
      if (c >= Ncols) continue;
      float bv = bias ? bias[c] : 0.f;
#pragma unroll
      for (int r = 0; r < 4; ++r) {
        int rr = bm + h * 16 + quad * 4 + r;
        if (rr >= M) continue;
        float v = acc[h][tn][r] + bv;
        if (actOut) v = siluf(v);
        if (C) C[(size_t)rr * ldc + c] = v;
        if (CH) {
          unsigned short hh = f2bf(v);
          CH[(size_t)rr * ldch + c] = hh;
          CL[(size_t)rr * ldch + c] = f2bf(v - bf2f(hh));
        }
      }
    }
  }
}

// --------- fused edge kernel: wave-private staging, no main-loop barriers
__global__ __launch_bounds__(256, 4) void k_edge_mfma(
    const float* __restrict__ Ab, const float* __restrict__ Bb,  // [N,644]+pad
    const int* __restrict__ ssrc, const int* __restrict__ sdst,
    const float* __restrict__ sd_g, int E,
    const unsigned short* __restrict__ WeaThi, const unsigned short* __restrict__ WeaTlo,
    const float* __restrict__ Wea64,
    const unsigned short* __restrict__ W2Thi, const unsigned short* __restrict__ W2Tlo,
    const float* __restrict__ b2v,
    const float* __restrict__ eng, const float* __restrict__ enb,
    float* __restrict__ msum) {
  __shared__ float sAB[4][16 * 68];  // wave-owned staging
  __shared__ float sH[4][16 * 68];   // wave-owned h tile; epilogue: sM stride 33
  __shared__ float sDs[64];
  __shared__ int sSrcS[64], sDstS[64];

  const int t = threadIdx.x;
  const int wave = t >> 6, lane = t & 63;
  const int nl = lane & 15, quad = lane >> 4;
  const int e0 = blockIdx.x * 64;

  if (lane < 16) {
    int el = wave * 16 + lane;
    int e = e0 + el;
    int ec = (e < E) ? e : (E - 1);
    sSrcS[el] = ssrc[ec];
    sDstS[el] = sdst[ec];
    sDs[el] = sd_g[ec];
  }

  // staging identity: lane stages row r (of wave's 16 edges), col-quarter cq
  const int r = lane >> 2, cq = lane & 3;
  const int elr = wave * 16 + r;
  const float* aRow = Ab + (size_t)sDstS[elr] * 644;
  const float* bRow = Bb + (size_t)sSrcS[elr] * 644;
  const float dRow = sDs[elr];
  float* myAB = sAB[wave];
  float* myH = sH[wave];

  f32x4 pa[4], pb[4];
  auto issue = [&](int c) {
    const int base = c * 64 + cq * 16;
    if (base + 15 < 642) {
#pragma unroll
      for (int j = 0; j < 4; ++j) {
        pa[j] = *(const f32x4*)(aRow + base + 4 * j);
        pb[j] = *(const f32x4*)(bRow + base + 4 * j);
      }
    } else {
#pragma unroll
      for (int j = 0; j < 4; ++j) {
#pragma unroll
        for (int u = 0; u < 4; ++u) {
          int col = base + 4 * j + u;
          pa[j][u] = (col < 642) ? aRow[col] : 0.f;
          pb[j][u] = (col < 642) ? bRow[col] : 0.f;
        }
      }
    }
  };
  auto commit = [&](int c) {
    const int base = c * 64 + cq * 16;
#pragma unroll
    for (int j = 0; j < 4; ++j) {
      f32x4 w;
      if (base + 15 < 642) {
        w = *(const f32x4*)(Wea64 + base + 4 * j);
      } else {
#pragma unroll
        for (int u = 0; u < 4; ++u) {
          int col = base + 4 * j + u;
          w[u] = (col < 642) ? Wea64[col] : 0.f;
        }
      }
      f32x4 o = pa[j] + pb[j] + dRow * w;
      *(f32x4*)(myAB + r * 68 + cq * 16 + 4 * j) = o;
    }
  };

  issue(0);  // gathers in flight while we compute sin/cos below

  // ea A-frags (register-resident), edge m = wave*16+nl
  bf16x8 eaHi[2], eaLo[2];
  {
    float d = sDs[wave * 16 + nl];
#pragma unroll
    for (int ks = 0; ks < 2; ++ks) {
#pragma unroll
      for (int j = 0; j < 8; ++j) {
        int k = ks * 32 + quad * 8 + j;
        float arg = d * exp2f(-(float)(k & 31));
        float v = (k < 32) ? sinf(arg) : cosf(arg);
        unsigned short h = f2bf(v);
        eaHi[ks][j] = (short)h;
        eaLo[ks][j] = (short)f2bf(v - bf2f(h));
      }
    }
  }

  f32x4 zero = {0.f, 0.f, 0.f, 0.f};
  f32x4 macc[2] = {zero, zero};

  for (int c = 0; c < 11; ++c) {
    commit(c);                 // vmcnt-wait own gathers; ds_write wave region
    if (c < 10) issue(c + 1);  // next gathers in flight during gemm1/gemm2
    // GEMM1: ea[16x64] @ Wea_chunk[64x64] -> C-layout acc1
    f32x4 acc1[4] = {zero, zero, zero, zero};
#pragma unroll
    for (int tn = 0; tn < 4; ++tn) {
      size_t base = (size_t)(c * 64 + tn * 16 + nl) * 64 + quad * 8;
#pragma unroll
      for (int ks = 0; ks < 2; ++ks) {
        bf16x8 bh = *(const bf16x8*)(WeaThi + base + ks * 32);
        bf16x8 bl = *(const bf16x8*)(WeaTlo + base + ks * 32);
        acc1[tn] = mfma16(eaHi[ks], bh, acc1[tn]);
        acc1[tn] = mfma16(eaHi[ks], bl, acc1[tn]);
        acc1[tn] = mfma16(eaLo[ks], bh, acc1[tn]);
      }
    }
#pragma unroll
    for (int tn = 0; tn < 4; ++tn) {
#pragma unroll
      for (int rr = 0; rr < 4; ++rr) {
        int lrow = quad * 4 + rr;
        float z = acc1[tn][rr] + myAB[lrow * 68 + tn * 16 + nl];
        myH[lrow * 68 + tn * 16 + nl] = siluf(z);
      }
    }
    // GEMM2: h[16x64] @ W2_chunk[64x32] accumulated (sH rows wave-owned)
#pragma unroll
    for (int ks = 0; ks < 2; ++ks) {
      f32x4 h0 = *(const f32x4*)(myH + nl * 68 + ks * 32 + quad * 8);
      f32x4 h1 = *(const f32x4*)(myH + nl * 68 + ks * 32 + quad * 8 + 4);
      float hv[8] = {h0.x, h0.y, h0.z, h0.w, h1.x, h1.y, h1.z, h1.w};
      bf16x8 ah, al;
#pragma unroll
      for (int j = 0; j < 8; ++j) {
        unsigned short hh = f2bf(hv[j]);
        ah[j] = (short)hh;
        al[j] = (short)f2bf(hv[j] - bf2f(hh));
      }
#pragma unroll
      for (int tn = 0; tn < 2; ++tn) {
        size_t base2 = (size_t)(tn * 16 + nl) * 704 + c * 64 + ks * 32 + quad * 8;
        bf16x8 bh = *(const bf16x8*)(W2Thi + base2);
        bf16x8 bl = *(const bf16x8*)(W2Tlo + base2);
        macc[tn] = mfma16(ah, bh, macc[tn]);
        macc[tn] = mfma16(ah, bl, macc[tn]);
        macc[tn] = mfma16(al, bh, macc[tn]);
      }
    }
  }

  // epilogue: bias+silu+LN(32) via width-16 shuffles -> wave-local sM region
  float g0 = eng[nl], g1v = eng[16 + nl], bb0 = enb[nl], bb1 = enb[16 + nl];
  float bi0 = b2v[nl], bi1 = b2v[16 + nl];
  float* sMw = myH;  // reuse own wave's sH region, rows 0..15 stride 33
#pragma unroll
  for (int rr = 0; rr < 4; ++rr) {
    float v0 = siluf(macc[0][rr] + bi0);
    float v1 = siluf(macc[1][rr] + bi1);
    float s = v0 + v1;
    float ss = v0 * v0 + v1 * v1;
#pragma unroll
    for (int m = 1; m < 16; m <<= 1) {
      s += __shfl_xor(s, m, 16);
      ss += __shfl_xor(ss, m, 16);
    }
    float mu = s * (1.f / 32.f);
    float var = ss * (1.f / 32.f) - mu * mu;
    float rs = rsqrtf(var + 1e-5f);
    int lr = quad * 4 + rr;
    sMw[lr * 33 + nl] = (v0 - mu) * rs * g0 + bb0;
    sMw[lr * 33 + 16 + nl] = (v1 - mu) * rs * g1v + bb1;
  }
  __syncthreads();  // the only barrier: cross-wave sM/sDstS visibility
  {
    int col = t & 31, seg = t >> 5;
    float acc = 0.f;
    int cur = -1;
#pragma unroll
    for (int i = 0; i < 8; ++i) {
      int e = seg * 8 + i;
      int dn = (e0 + e < E) ? sDstS[e] : -1;
      if (dn != cur) {
        if (cur >= 0) atomicAdd(&msum[(size_t)cur * 32 + col], acc);
        acc = 0.f;
        cur = dn;
      }
      if (dn >= 0) acc += sH[e >> 4][(e & 15) * 33 + col];
    }
    if (cur >= 0) atomicAdd(&msum[(size_t)cur * 32 + col], acc);
  }
}

// ------------------------------- node-side LN + concat builder (hi/lo out)
__global__ __launch_bounds__(256) void k_node_ln(
    const float* __restrict__ msum, const float* __restrict__ deg,
    const float* __restrict__ featsAll, int k,
    const float* __restrict__ n1g, const float* __restrict__ n1b,
    const float* __restrict__ eng, const float* __restrict__ enb,
    unsigned short* __restrict__ hcatH, unsigned short* __restrict__ hcatL, int N) {
  int node = blockIdx.x * 4 + (threadIdx.x >> 6);
  int lane = threadIdx.x & 63;
  if (node >= N) return;
  const float* fr = featsAll + (size_t)node * 768 + k * 128;
  float x0 = fr[lane], x1 = fr[64 + lane];
  float s = x0 + x1;
#pragma unroll
  for (int m = 1; m < 64; m <<= 1) s += __shfl_xor(s, m, 64);
  float mu = s * (1.f / 128.f);
  float d0 = x0 - mu, d1 = x1 - mu;
  float v = d0 * d0 + d1 * d1;
#pragma unroll
  for (int m = 1; m < 64; m <<= 1) v += __shfl_xor(v, m, 64);
  float rstd = rsqrtf(v * (1.f / 128.f) + 1e-5f);
  size_t hb = (size_t)node * 160;
  float o0 = d0 * rstd * n1g[lane] + n1b[lane];
  float o1 = d1 * rstd * n1g[64 + lane] + n1b[64 + lane];
  unsigned short h0 = f2bf(o0), h1 = f2bf(o1);
  hcatH[hb + lane] = h0; hcatL[hb + lane] = f2bf(o0 - bf2f(h0));
  hcatH[hb + 64 + lane] = h1; hcatL[hb + 64 + lane] = f2bf(o1 - bf2f(h1));
  float dg = deg[node];
  int col = lane & 31;
  float y = msum[(size_t)node * 32 + col] / dg;
  float sy = y;
#pragma unroll
  for (int m = 1; m < 32; m <<= 1) sy += __shfl_xor(sy, m, 32);
  float mu2 = sy * (1.f / 32.f);
  float dy = y - mu2;
  float vy = dy * dy;
#pragma unroll
  for (int m = 1; m < 32; m <<= 1) vy += __shfl_xor(vy, m, 32);
  float rstd2 = rsqrtf(vy * (1.f / 32.f) + 1e-5f);
  if (lane < 32) {
    float o2 = dy * rstd2 * eng[col] + enb[col];
    unsigned short h2 = f2bf(o2);
    hcatH[hb + 128 + col] = h2;
    hcatL[hb + 128 + col] = f2bf(o2 - bf2f(h2));
  }
}

// -------------------------------- node residual + final LN (+hi/lo slice)
__global__ __launch_bounds__(256) void k_node_resid(
    const float* __restrict__ t2, float* __restrict__ featsAll, int k,
    const float* __restrict__ n2g, const float* __restrict__ n2b,
    unsigned short* __restrict__ fH, unsigned short* __restrict__ fL, int N) {
  int node = blockIdx.x * 4 + (threadIdx.x >> 6);
  int lane = threadIdx.x & 63;
  if (node >= N) return;
  const float* tr = t2 + (size_t)node * 128;
  float x0 = tr[lane], x1 = tr[64 + lane];
  float s = x0 + x1;
#pragma unroll
  for (int m = 1; m < 64; m <<= 1) s += __shfl_xor(s, m, 64);
  float mu = s * (1.f / 128.f);
  float d0 = x0 - mu, d1 = x1 - mu;
  float v = d0 * d0 + d1 * d1;
#pragma unroll
  for (int m = 1; m < 64; m <<= 1) v += __shfl_xor(v, m, 64);
  float rstd = rsqrtf(v * (1.f / 128.f) + 1e-5f);
  const float* fk = featsAll + (size_t)node * 768 + k * 128;
  size_t ob = (size_t)node * 768 + (k + 1) * 128;
  float o0 = fk[lane] + d0 * rstd * n2g[lane] + n2b[lane];
  float o1 = fk[64 + lane] + d1 * rstd * n2g[64 + lane] + n2b[64 + lane];
  featsAll[ob + lane] = o0;
  featsAll[ob + 64 + lane] = o1;
  unsigned short h0 = f2bf(o0), h1 = f2bf(o1);
  fH[ob + lane] = h0; fL[ob + lane] = f2bf(o0 - bf2f(h0));
  fH[ob + 64 + lane] = h1; fL[ob + 64 + lane] = f2bf(o1 - bf2f(h1));
}

// ------------------------------------- graph pooling (batch sorted -> runs)
__global__ __launch_bounds__(256) void k_pool2(const float* __restrict__ f,
                                               const int* __restrict__ batch,
                                               float* __restrict__ gsum,
                                               float* __restrict__ gcnt, int N) {
  int n0 = blockIdx.x * 64;
  int col = threadIdx.x;
  float acc = 0.f;
  int cur = -1;
  for (int i = 0; i < 64; ++i) {
    int n = n0 + i;
    if (n >= N) break;
    int b = batch[n];
    if (b != cur) {
      if (cur >= 0) atomicAdd(&gsum[cur * 256 + col], acc);
      acc = 0.f;
      cur = b;
    }
    acc += f[(size_t)n * 256 + col];
  }
  if (cur >= 0) atomicAdd(&gsum[cur * 256 + col], acc);
  if (threadIdx.x == 0) {
    int cnt = 0;
    cur = -1;
    for (int i = 0; i < 64; ++i) {
      int n = n0 + i;
      if (n >= N) break;
      int b = batch[n];
      if (b != cur) {
        if (cur >= 0) atomicAdd(&gcnt[cur], (float)cnt);
        cnt = 0;
        cur = b;
      }
      cnt++;
    }
    if (cur >= 0) atomicAdd(&gcnt[cur], (float)cnt);
  }
}

__global__ void k_gdiv(float* gsum, const float* gcnt,
                       unsigned short* gH, unsigned short* gL) {
  int b = blockIdx.x, j = threadIdx.x;
  float v = gsum[b * 256 + j] / fmaxf(gcnt[b], 1.f);
  gsum[b * 256 + j] = v;
  unsigned short h = f2bf(v);
  gH[b * 256 + j] = h;
  gL[b * 256 + j] = f2bf(v - bf2f(h));
}

__global__ void k_gout(const float* __restrict__ g2, const float* __restrict__ gW2,
                       const float* __restrict__ gb2, float* __restrict__ out) {
  int b = threadIdx.x;
  if (b >= 64) return;
  float s = gb2[0];
  for (int j = 0; j < 256; ++j) s += g2[b * 256 + j] * gW2[j];
  out[b] = s;
}

// ------------------------------------------------------------------- launch
extern "C" void kernel_launch(void* const* d_in, const int* in_sizes, int n_in,
                              void* d_out, int out_size, void* d_ws, size_t ws_size,
                              hipStream_t stream) {
  const float* coords = (const float*)d_in[0];
  const int* atomids = (const int*)d_in[1];
  const int* ei = (const int*)d_in[2];
  const int* batch = (const int*)d_in[3];
  const float* emb = (const float*)d_in[5];
  const float* keW1 = (const float*)d_in[6];
  const float* keb1 = (const float*)d_in[7];
  const float* keW2 = (const float*)d_in[8];
  const float* keb2 = (const float*)d_in[9];
  const float* keng = (const float*)d_in[10];
  const float* kenb = (const float*)d_in[11];
  const float* kn1g = (const float*)d_in[12];
  const float* kn1b = (const float*)d_in[13];
  const float* knW1 = (const float*)d_in[14];
  const float* knb1 = (const float*)d_in[15];
  const float* knW2 = (const float*)d_in[16];
  const float* knb2 = (const float*)d_in[17];
  const float* kn2g = (const float*)d_in[18];
  const float* kn2b = (const float*)d_in[19];
  const float* fW0 = (const float*)d_in[20];
  const float* fb0 = (const float*)d_in[21];
  const float* fW1 = (const float*)d_in[22];
  const float* fb1 = (const float*)d_in[23];
  const float* fW2 = (const float*)d_in[24];
  const float* fb2 = (const float*)d_in[25];
  const float* gW0 = (const float*)d_in[26];
  const float* gb0 = (const float*)d_in[27];
  const float* gW1 = (const float*)d_in[28];
  const float* gb1 = (const float*)d_in[29];
  const float* gW2 = (const float*)d_in[30];
  const float* gb2 = (const float*)d_in[31];

  const int N = in_sizes[0] / 3;
  const int E = in_sizes[2] / 2;

  size_t off = 0;
  auto alloc = [&](size_t n) {
    float* p = (float*)d_ws + off;
    off += (n + 63) & ~(size_t)63;
    return p;
  };
  float* feats_all = alloc((size_t)N * 768);
  float* d_arr = alloc(E);
  float* degf = alloc(N);
  float* msum = alloc((size_t)N * 32);
  float* Abuf = alloc((size_t)N * 644 + 256);
  float* Bbuf = alloc((size_t)N * 644 + 256);
  float* gsum = alloc(64 * 256);
  float* gcnt = alloc(64);
  float* g2 = alloc(64 * 256);
  int* cnt = (int*)alloc(N);
  int* cursor = (int*)alloc(N);
  int* ssrc = (int*)alloc(E);
  int* sdst = (int*)alloc(E);
  float* sd = alloc(E);

  // node-MLP phase aliases inside Abuf (bytes: N*832*2 + N*512 <= N*2576)
  unsigned short* hcatH = (unsigned short*)Abuf;
  unsigned short* hcatL = hcatH + (size_t)N * 160;
  unsigned short* t1H = hcatL + (size_t)N * 160;
  unsigned short* t1L = t1H + (size_t)N * 256;
  float* t2 = (float*)(t1L + (size_t)N * 256);
  // fnn-phase aliases: Bbuf (hi/lo chains), Abuf (final f fp32)
  unsigned short* fAH = (unsigned short*)Bbuf;
  unsigned short* fAL = fAH + (size_t)N * 256;
  unsigned short* fBH = fAL + (size_t)N * 256;
  unsigned short* fBL = fBH + (size_t)N * 256;
  float* f1 = Abuf;

  unsigned short* ubase = (unsigned short*)(alloc(0));
  size_t uoff = 0;
  auto ualloc = [&](size_t n) {
    unsigned short* p = ubase + uoff;
    uoff += (n + 63) & ~(size_t)63;
    return p;
  };
  unsigned short* fH = ualloc((size_t)N * 768);
  unsigned short* fL = ualloc((size_t)N * 768);
  const size_t sDst_ = 704 * 128, sSrc_ = 704 * 128, sEa_ = 704 * 64;
  const size_t sW2_ = 32 * 704, sN1_ = 256 * 160, sN2_ = 128 * 256;
  unsigned short* PdstH = ualloc(5 * sDst_); unsigned short* PdstL = ualloc(5 * sDst_);
  unsigned short* PsrcH = ualloc(5 * sSrc_); unsigned short* PsrcL = ualloc(5 * sSrc_);
  unsigned short* PeaH = ualloc(5 * sEa_);   unsigned short* PeaL = ualloc(5 * sEa_);
  unsigned short* PW2H = ualloc(5 * sW2_);   unsigned short* PW2L = ualloc(5 * sW2_);
  unsigned short* Pn1H = ualloc(5 * sN1_);   unsigned short* Pn1L = ualloc(5 * sN1_);
  unsigned short* Pn2H = ualloc(5 * sN2_);   unsigned short* Pn2L = ualloc(5 * sN2_);
  unsigned short* Pf0H = ualloc(256 * 768);  unsigned short* Pf0L = ualloc(256 * 768);
  unsigned short* Pf1H = ualloc(256 * 256);  unsigned short* Pf1L = ualloc(256 * 256);
  unsigned short* Pf2H = ualloc(256 * 256);  unsigned short* Pf2L = ualloc(256 * 256);
  unsigned short* Pg0H = ualloc(256 * 256);  unsigned short* Pg0L = ualloc(256 * 256);
  unsigned short* Pg1H = ualloc(256 * 256);  unsigned short* Pg1L = ualloc(256 * 256);
  unsigned short* gH = ualloc(64 * 256);     unsigned short* gL = ualloc(64 * 256);
  unsigned short* g1H = ualloc(64 * 256);    unsigned short* g1L = ualloc(64 * 256);

  auto pp = [&](const float* W, size_t wStr, int ldw, int K, int Kpad, int Nc, int Npad,
                unsigned short* hi, unsigned short* lo, size_t oStr, int layers) {
    int total = Npad * Kpad;
    k_prepack<<<dim3((total + 255) / 256, layers), 256, 0, stream>>>(
        W, wStr, ldw, K, Kpad, Nc, Npad, hi, lo, oStr);
  };
  pp(keW1, (size_t)321 * 642, 642, 128, 128, 642, 704, PdstH, PdstL, sDst_, 5);
  pp(keW1 + 128 * 642, (size_t)321 * 642, 642, 128, 128, 642, 704, PsrcH, PsrcL, sSrc_, 5);
  pp(keW1 + 256 * 642, (size_t)321 * 642, 642, 64, 64, 642, 704, PeaH, PeaL, sEa_, 5);
  pp(keW2, (size_t)642 * 32, 32, 642, 704, 32, 32, PW2H, PW2L, sW2_, 5);
  pp(knW1, (size_t)160 * 256, 256, 160, 160, 256, 256, Pn1H, Pn1L, sN1_, 5);
  pp(knW2, (size_t)256 * 128, 128, 256, 256, 128, 128, Pn2H, Pn2L, sN2_, 5);
  pp(fW0, 0, 256, 768, 768, 256, 256, Pf0H, Pf0L, 0, 1);
  pp(fW1, 0, 256, 256, 256, 256, 256, Pf1H, Pf1L, 0, 1);
  pp(fW2, 0, 256, 256, 256, 256, 256, Pf2H, Pf2L, 0, 1);
  pp(gW0, 0, 256, 256, 256, 256, 256, Pg0H, Pg0L, 0, 1);
  pp(gW1, 0, 256, 256, 256, 256, 256, Pg1H, Pg1L, 0, 1);

  // ---- node feats + edge sort by dst (counting sort)
  k_gather<<<(N * 128 + 255) / 256, 256, 0, stream>>>(atomids, emb, feats_all, fH, fL, N);
  hipMemsetAsync(cnt, 0, (size_t)N * sizeof(int), stream);
  k_edge_prep<<<(E + 255) / 256, 256, 0, stream>>>(coords, ei, E, d_arr, cnt);
  k_scan<<<1, 1024, 0, stream>>>(cnt, N, cursor, degf);
  k_scatter<<<(E + 255) / 256, 256, 0, stream>>>(ei, E, d_arr, cursor, ssrc, sdst, sd);

  const int MT = (N + 127) / 128;
  for (int k = 0; k < 5; ++k) {
    gemm_bf<<<dim3(MT, 11), 256, 0, stream>>>(
        fH + k * 128, fL + k * 128, 768, PdstH + k * sDst_, PdstL + k * sDst_, 128,
        keb1 + k * 642, Abuf, 644, nullptr, nullptr, 0, N, 642, 128, 0, 0);
    gemm_bf<<<dim3(MT, 11), 256, 0, stream>>>(
        fH + k * 128, fL + k * 128, 768, PsrcH + k * sSrc_, PsrcL + k * sSrc_, 128,
        nullptr, Bbuf, 644, nullptr, nullptr, 0, N, 642, 128, 0, 0);
    hipMemsetAsync(msum, 0, (size_t)N * 32 * sizeof(float), stream);
    k_edge_mfma<<<(E + 63) / 64, 256, 0, stream>>>(
        Abuf, Bbuf, ssrc, sdst, sd, E,
        PeaH + k * sEa_, PeaL + k * sEa_,
        keW1 + (size_t)k * 321 * 642 + (size_t)320 * 642,
        PW2H + k * sW2_, PW2L + k * sW2_,
        keb2 + k * 32, keng + k * 32, kenb + k * 32, msum);
    k_node_ln<<<(N + 3) / 4, 256, 0, stream>>>(
        msum, degf, feats_all, k, kn1g + k * 128, kn1b + k * 128,
        keng + k * 32, kenb + k * 32, hcatH, hcatL, N);
    gemm_bf<<<dim3(MT, 4), 256, 0, stream>>>(
        hcatH, hcatL, 160, Pn1H + k * sN1_, Pn1L + k * sN1_, 160,
        knb1 + k * 256, nullptr, 0, t1H, t1L, 256, N, 256, 160, 1, 0);
    gemm_bf<<<dim3(MT, 2), 256, 0, stream>>>(
        t1H, t1L, 256, Pn2H + k * sN2_, Pn2L + k * sN2_, 256,
        knb2 + k * 128, t2, 128, nullptr, nullptr, 0, N, 128, 256, 0, 0);
    k_node_resid<<<(N + 3) / 4, 256, 0, stream>>>(
        t2, feats_all, k, kn2g + k * 128, kn2b + k * 128, fH, fL, N);
  }

  gemm_bf<<<dim3(MT, 4), 256, 0, stream>>>(
      fH, fL, 768, Pf0H, Pf0L, 768, fb0, nullptr, 0, fAH, fAL, 256,
      N, 256, 768, 1, 1);
  gemm_bf<<<dim3(MT, 4), 256, 0, stream>>>(
      fAH, fAL, 256, Pf1H, Pf1L, 256, fb1, nullptr, 0, fBH, fBL, 256,
      N, 256, 256, 1, 0);
  gemm_bf<<<dim3(MT, 4), 256, 0, stream>>>(
      fBH, fBL, 256, Pf2H, Pf2L, 256, fb2, f1, 256, nullptr, nullptr, 0,
      N, 256, 256, 1, 0);

  hipMemsetAsync(gsum, 0, 64 * 256 * sizeof(float), stream);
  hipMemsetAsync(gcnt, 0, 64 * sizeof(float), stream);
  k_pool2<<<(N + 63) / 64, 256, 0, stream>>>(f1, batch, gsum, gcnt, N);
  k_gdiv<<<64, 256, 0, stream>>>(gsum, gcnt, gH, gL);
  gemm_bf<<<dim3(1, 4), 256, 0, stream>>>(
      gH, gL, 256, Pg0H, Pg0L, 256, gb0, nullptr, 0, g1H, g1L, 256,
      64, 256, 256, 1, 0);
  gemm_bf<<<dim3(1, 4), 256, 0, stream>>>(
      g1H, g1L, 256, Pg1H, Pg1L, 256, gb1, g2, 256, nullptr, nullptr, 0,
      64, 256, 256, 1, 0);
  k_gout<<<1, 64, 0, stream>>>(g2, gW2, gb2, (float*)d_out);
}

// Round 6
// 1868.138 us; speedup vs baseline: 1.6098x; 1.5403x over previous
//
#include <hip/hip_runtime.h>
#include <cstdint>
#include <cstddef>

// DeltaNetMolecular R6: bf16 chunk-plane A/B gathers ([11][N][64] layout, 128B
// rows), register-pipelined edge weights (one vmcnt drain per chunk, no
// intermediate waits, no main-loop barriers), single-bf16 edge MFMAs,
// __sinf/__cosf, dense GEMMs = bf16 activations x hi/lo-bf16 weights (2 MFMA).

#define DEV __device__ __forceinline__

typedef __attribute__((ext_vector_type(8))) short bf16x8;
typedef __attribute__((ext_vector_type(4))) float f32x4;

DEV float siluf(float x) { return x / (1.f + __expf(-x)); }

DEV unsigned short f2bf(float f) {
  unsigned u = __float_as_uint(f);
  unsigned r = u + 0x7FFFu + ((u >> 16) & 1u);
  return (unsigned short)(r >> 16);
}
DEV float bf2f(unsigned short h) { return __uint_as_float(((unsigned)h) << 16); }

DEV f32x4 mfma16(bf16x8 a, bf16x8 b, f32x4 c) {
  return __builtin_amdgcn_mfma_f32_16x16x32_bf16(a, b, c, 0, 0, 0);
}

DEV void unpack8(bf16x8 v, float* o) {
#pragma unroll
  for (int j = 0; j < 8; ++j) o[j] = bf2f((unsigned short)v[j]);
}

// ------------------------------------------------- gather emb (+bf16 copy)
__global__ __launch_bounds__(256) void k_gather(const int* __restrict__ atomids,
                                                const float* __restrict__ emb,
                                                float* __restrict__ feats_all,
                                                unsigned short* __restrict__ fH, int N) {
  int idx = blockIdx.x * 256 + threadIdx.x;
  if (idx >= N * 128) return;
  int i = idx >> 7, j = idx & 127;
  float v = emb[atomids[i] * 128 + j];
  size_t o = (size_t)i * 768 + j;
  feats_all[o] = v;
  fH[o] = f2bf(v);
}

// --------------------------------------------------- edge dist + dst histogram
__global__ __launch_bounds__(256) void k_edge_prep(const float* __restrict__ coords,
                                                   const int* __restrict__ ei, int E,
                                                   float* __restrict__ d_arr,
                                                   int* __restrict__ cnt) {
  int e = blockIdx.x * 256 + threadIdx.x;
  if (e >= E) return;
  int s = ei[e], t = ei[E + e];
  float dx = coords[3 * s + 0] - coords[3 * t + 0];
  float dy = coords[3 * s + 1] - coords[3 * t + 1];
  float dz = coords[3 * s + 2] - coords[3 * t + 2];
  d_arr[e] = dx * dx + dy * dy + dz * dz;
  atomicAdd(&cnt[t], 1);
}

// ------------------------------------------- single-block scan (N <= ~64K ok)
__global__ __launch_bounds__(1024) void k_scan(const int* __restrict__ cnt, int N,
                                               int* __restrict__ cursor,
                                               float* __restrict__ degf) {
  __shared__ int s[1024];
  __shared__ int carry;
  if (threadIdx.x == 0) carry = 0;
  __syncthreads();
  for (int base = 0; base < N; base += 1024) {
    int i = base + threadIdx.x;
    int v = (i < N) ? cnt[i] : 0;
    s[threadIdx.x] = v;
    __syncthreads();
    for (int off = 1; off < 1024; off <<= 1) {
      int add = (threadIdx.x >= off) ? s[threadIdx.x - off] : 0;
      __syncthreads();
      s[threadIdx.x] += add;
      __syncthreads();
    }
    if (i < N) {
      cursor[i] = s[threadIdx.x] - v + carry;
      degf[i] = fmaxf((float)v, 1.f);
    }
    __syncthreads();
    if (threadIdx.x == 0) carry += s[1023];
    __syncthreads();
  }
}

// ------------------------------------------------------- scatter sorted edges
__global__ __launch_bounds__(256) void k_scatter(const int* __restrict__ ei, int E,
                                                 const float* __restrict__ d_arr,
                                                 int* __restrict__ cursor,
                                                 int* __restrict__ ssrc,
                                                 int* __restrict__ sdst,
                                                 float* __restrict__ sd) {
  int e = blockIdx.x * 256 + threadIdx.x;
  if (e >= E) return;
  int s = ei[e], t = ei[E + e];
  int p = atomicAdd(&cursor[t], 1);
  ssrc[p] = s;
  sdst[p] = t;
  sd[p] = d_arr[e];
}

// ----------------------------------------------------- weight prepack (hi/lo)
__global__ __launch_bounds__(256) void k_prepack(
    const float* __restrict__ W, size_t wStride, int ldw,
    int K, int Kpad, int Ncols, int Npad,
    unsigned short* __restrict__ hi, unsigned short* __restrict__ lo, size_t oStride) {
  int idx = blockIdx.x * 256 + threadIdx.x;
  int total = Npad * Kpad;
  if (idx >= total) return;
  W += blockIdx.y * wStride;
  hi += blockIdx.y * oStride;
  lo += blockIdx.y * oStride;
  int n = idx / Kpad, k = idx - n * Kpad;
  float v = (n < Ncols && k < K) ? W[(size_t)k * ldw + n] : 0.f;
  unsigned short h = f2bf(v);
  hi[idx] = h;
  lo[idx] = f2bf(v - bf2f(h));
}

// --------- bf16 MFMA GEMM: A bf16 single, B hi/lo x2 (M=128 per block)
__global__ __launch_bounds__(256) void gemm_bf(
    const unsigned short* __restrict__ AH, int lda,
    const unsigned short* __restrict__ BH, const unsigned short* __restrict__ BL, int ldb,
    const float* __restrict__ bias,
    float* __restrict__ C, int ldc,
    unsigned short* __restrict__ CH, int ldch, int outPlaneN,  // >0: plane-major
    int M, int Ncols, int K, int actOut, int actA) {
  const int t = threadIdx.x;
  const int wave = t >> 6, lane = t & 63;
  const int nl = lane & 15, quad = lane >> 4;
  const int bm = blockIdx.x * 128 + wave * 32;
  const int bn = blockIdx.y * 64;
  f32x4 zero = {0.f, 0.f, 0.f, 0.f};
  f32x4 acc[2][4] = {{zero, zero, zero, zero}, {zero, zero, zero, zero}};
  for (int kb = 0; kb < K; kb += 32) {
    bf16x8 ah[2];
#pragma unroll
    for (int h = 0; h < 2; ++h) {
      int row = bm + h * 16 + nl;
      if (row < M) {
        ah[h] = *(const bf16x8*)(AH + (size_t)row * lda + kb + quad * 8);
        if (actA) {
#pragma unroll
          for (int j = 0; j < 8; ++j) {
            float a = siluf(bf2f((unsigned short)ah[h][j]));
            ah[h][j] = (short)f2bf(a);
          }
        }
      } else {
#pragma unroll
        for (int j = 0; j < 8; ++j) ah[h][j] = 0;
      }
    }
#pragma unroll
    for (int tn = 0; tn < 4; ++tn) {
      size_t boff = (size_t)(bn + tn * 16 + nl) * ldb + kb + quad * 8;
      bf16x8 bh = *(const bf16x8*)(BH + boff);
      bf16x8 bl = *(const bf16x8*)(BL + boff);
#pragma unroll
      for (int h = 0; h < 2; ++h) {
        acc[h][tn] = mfma16(ah[h], bh, acc[h][tn]);
        acc[h][tn] = mfma16(ah[h], bl, acc[h][tn]);
      }
    }
  }
#pragma unroll
  for (int h = 0; h < 2; ++h) {
#pragma unroll
    for (int tn = 0; tn < 4; ++tn) {
      int c = bn + tn * 16 + nl;
      float bv = (bias && c < Ncols) ? bias[c] : 0.f;
#pragma unroll
      for (int r = 0; r < 4; ++r) {
        int rr = bm + h * 16 + quad * 4 + r;
        if (rr >= M) continue;
        float v = acc[h][tn][r] + bv;
        if (actOut) v = siluf(v);
        if (C && c < Ncols) C[(size_t)rr * ldc + c] = v;
        if (CH) {
          unsigned short us = f2bf(v);
          if (outPlaneN > 0)
            CH[(size_t)blockIdx.y * outPlaneN + (size_t)rr * 64 + tn * 16 + nl] = us;
          else if (c < Ncols)
            CH[(size_t)rr * ldch + c] = us;
        }
      }
    }
  }
}

// --- fused edge kernel: bf16 plane gathers, reg-pipelined weights, no barriers
__global__ __launch_bounds__(256, 3) void k_edge_mfma(
    const unsigned short* __restrict__ Ap, const unsigned short* __restrict__ Bp,
    int planeN,  // N*64
    const int* __restrict__ ssrc, const int* __restrict__ sdst,
    const float* __restrict__ sd_g, int E,
    const unsigned short* __restrict__ WeaT,  // [704][64] bf16 hi
    const float* __restrict__ Wea64,          // [642] fp32 (d-row of W1)
    const unsigned short* __restrict__ W2T,   // [32][704] bf16 hi
    const float* __restrict__ b2v,
    const float* __restrict__ eng, const float* __restrict__ enb,
    float* __restrict__ msum) {
  __shared__ float sAB[4][16 * 68];
  __shared__ float sH[4][16 * 68];
  __shared__ float sDs[64];
  __shared__ int sSrcS[64], sDstS[64];

  const int t = threadIdx.x;
  const int wave = t >> 6, lane = t & 63;
  const int nl = lane & 15, quad = lane >> 4;
  const int e0 = blockIdx.x * 64;

  if (lane < 16) {
    int el = wave * 16 + lane;
    int e = e0 + el;
    int ec = (e < E) ? e : (E - 1);
    sSrcS[el] = ssrc[ec];
    sDstS[el] = sdst[ec];
    sDs[el] = sd_g[ec];
  }
  // same-wave LDS ordering: no barrier needed (wave-private regions)
  const int r = lane >> 2, cq = lane & 3;
  const int elr = wave * 16 + r;
  const size_t aOff = (size_t)sDstS[elr] * 64 + cq * 16;
  const size_t bOff = (size_t)sSrcS[elr] * 64 + cq * 16;
  const float dR = sDs[elr];
  float* myAB = sAB[wave];
  float* myH = sH[wave];

  bf16x8 pa0, pa1, pb0, pb1;
  bf16x8 w1[4][2], w2a[2][2], w2b[2][2];

  auto loadW1 = [&](int c) {
#pragma unroll
    for (int tn = 0; tn < 4; ++tn)
#pragma unroll
      for (int ks = 0; ks < 2; ++ks)
        w1[tn][ks] = *(const bf16x8*)(WeaT + (size_t)(c * 64 + tn * 16 + nl) * 64 +
                                      ks * 32 + quad * 8);
  };
  auto loadW2 = [&](int c, bf16x8(*w)[2]) {
#pragma unroll
    for (int tn = 0; tn < 2; ++tn)
#pragma unroll
      for (int ks = 0; ks < 2; ++ks)
        w[tn][ks] = *(const bf16x8*)(W2T + (size_t)(tn * 16 + nl) * 704 + c * 64 +
                                     ks * 32 + quad * 8);
  };
  auto issue = [&](int c) {
    const unsigned short* a = Ap + (size_t)c * planeN + aOff;
    const unsigned short* b = Bp + (size_t)c * planeN + bOff;
    pa0 = *(const bf16x8*)a;
    pa1 = *(const bf16x8*)(a + 8);
    pb0 = *(const bf16x8*)b;
    pb1 = *(const bf16x8*)(b + 8);
  };
  auto commit = [&](int c) {
    float za[16], zb[16], w[16];
    unpack8(pa0, za); unpack8(pa1, za + 8);
    unpack8(pb0, zb); unpack8(pb1, zb + 8);
    const int cb = c * 64 + cq * 16;
    if (cb + 15 < 642) {
#pragma unroll
      for (int j = 0; j < 4; ++j) {
        f32x4 wv = *(const f32x4*)(Wea64 + cb + 4 * j);
        w[4 * j] = wv.x; w[4 * j + 1] = wv.y; w[4 * j + 2] = wv.z; w[4 * j + 3] = wv.w;
      }
    } else {
#pragma unroll
      for (int u = 0; u < 16; ++u) w[u] = (cb + u < 642) ? Wea64[cb + u] : 0.f;
    }
#pragma unroll
    for (int j = 0; j < 4; ++j) {
      f32x4 o;
#pragma unroll
      for (int u = 0; u < 4; ++u) o[u] = za[4 * j + u] + zb[4 * j + u] + dR * w[4 * j + u];
      *(f32x4*)(myAB + r * 68 + cq * 16 + 4 * j) = o;
    }
  };

  // ea A-frags (register-resident, bf16), edge m = wave*16+nl
  issue(0);
  bf16x8 eaHi[2];
  {
    float d = sDs[wave * 16 + nl];
#pragma unroll
    for (int ks = 0; ks < 2; ++ks)
#pragma unroll
      for (int j = 0; j < 8; ++j) {
        int k = ks * 32 + quad * 8 + j;
        float arg = d * exp2f(-(float)(k & 31));
        float v = (k < 32) ? __sinf(arg) : __cosf(arg);
        eaHi[ks][j] = (short)f2bf(v);
      }
  }
  loadW1(0);
  loadW2(0, w2a);

  f32x4 zero = {0.f, 0.f, 0.f, 0.f};
  f32x4 macc[2] = {zero, zero};

#pragma unroll
  for (int c = 0; c < 11; ++c) {
    commit(c);                 // the single vmcnt drain per chunk
    if (c < 10) issue(c + 1);  // gathers fly for a full chunk (no waits below)
    // GEMM1 with in-register weights
    f32x4 acc1[4] = {zero, zero, zero, zero};
#pragma unroll
    for (int tn = 0; tn < 4; ++tn)
#pragma unroll
      for (int ks = 0; ks < 2; ++ks) acc1[tn] = mfma16(eaHi[ks], w1[tn][ks], acc1[tn]);
#pragma unroll
    for (int tn = 0; tn < 4; ++tn)
#pragma unroll
      for (int rr = 0; rr < 4; ++rr) {
        int lrow = quad * 4 + rr;
        float z = acc1[tn][rr] + myAB[lrow * 68 + tn * 16 + nl];
        myH[lrow * 68 + tn * 16 + nl] = siluf(z);
      }
    if (c < 10) {
      loadW1(c + 1);                         // w1 dead after gemm1 -> reuse
      loadW2(c + 1, (c & 1) ? w2a : w2b);    // double-buffered
    }
    // GEMM2 with in-register weights (sH rows wave-owned)
    bf16x8(*w2)[2] = (c & 1) ? w2b : w2a;
#pragma unroll
    for (int ks = 0; ks < 2; ++ks) {
      f32x4 h0 = *(const f32x4*)(myH + nl * 68 + ks * 32 + quad * 8);
      f32x4 h1 = *(const f32x4*)(myH + nl * 68 + ks * 32 + quad * 8 + 4);
      bf16x8 ah;
      ah[0] = (short)f2bf(h0.x); ah[1] = (short)f2bf(h0.y);
      ah[2] = (short)f2bf(h0.z); ah[3] = (short)f2bf(h0.w);
      ah[4] = (short)f2bf(h1.x); ah[5] = (short)f2bf(h1.y);
      ah[6] = (short)f2bf(h1.z); ah[7] = (short)f2bf(h1.w);
#pragma unroll
      for (int tn = 0; tn < 2; ++tn) macc[tn] = mfma16(ah, w2[tn][ks], macc[tn]);
    }
  }

  // epilogue: bias+silu+LN(32) via width-16 shuffles -> wave-local sM region
  float g0 = eng[nl], g1v = eng[16 + nl], bb0 = enb[nl], bb1 = enb[16 + nl];
  float bi0 = b2v[nl], bi1 = b2v[16 + nl];
  float* sMw = myH;  // rows 0..15 stride 33
#pragma unroll
  for (int rr = 0; rr < 4; ++rr) {
    float v0 = siluf(macc[0][rr] + bi0);
    float v1 = siluf(macc[1][rr] + bi1);
    float s = v0 + v1;
    float ss = v0 * v0 + v1 * v1;
#pragma unroll
    for (int m = 1; m < 16; m <<= 1) {
      s += __shfl_xor(s, m, 16);
      ss += __shfl_xor(ss, m, 16);
    }
    float mu = s * (1.f / 32.f);
    float var = ss * (1.f / 32.f) - mu * mu;
    float rs = rsqrtf(var + 1e-5f);
    int lr = quad * 4 + rr;
    sMw[lr * 33 + nl] = (v0 - mu) * rs * g0 + bb0;
    sMw[lr * 33 + 16 + nl] = (v1 - mu) * rs * g1v + bb1;
  }
  __syncthreads();  // only barrier: cross-wave sM/sDstS visibility
  {
    int col = t & 31, seg = t >> 5;
    float acc = 0.f;
    int cur = -1;
#pragma unroll
    for (int i = 0; i < 8; ++i) {
      int e = seg * 8 + i;
      int dn = (e0 + e < E) ? sDstS[e] : -1;
      if (dn != cur) {
        if (cur >= 0) atomicAdd(&msum[(size_t)cur * 32 + col], acc);
        acc = 0.f;
        cur = dn;
      }
      if (dn >= 0) acc += sH[e >> 4][(e & 15) * 33 + col];
    }
    if (cur >= 0) atomicAdd(&msum[(size_t)cur * 32 + col], acc);
  }
}

// ------------------------------- node-side LN + concat builder (bf16 out)
__global__ __launch_bounds__(256) void k_node_ln(
    const float* __restrict__ msum, const float* __restrict__ deg,
    const float* __restrict__ featsAll, int k,
    const float* __restrict__ n1g, const float* __restrict__ n1b,
    const float* __restrict__ eng, const float* __restrict__ enb,
    unsigned short* __restrict__ hcatH, int N) {
  int node = blockIdx.x * 4 + (threadIdx.x >> 6);
  int lane = threadIdx.x & 63;
  if (node >= N) return;
  const float* fr = featsAll + (size_t)node * 768 + k * 128;
  float x0 = fr[lane], x1 = fr[64 + lane];
  float s = x0 + x1;
#pragma unroll
  for (int m = 1; m < 64; m <<= 1) s += __shfl_xor(s, m, 64);
  float mu = s * (1.f / 128.f);
  float d0 = x0 - mu, d1 = x1 - mu;
  float v = d0 * d0 + d1 * d1;
#pragma unroll
  for (int m = 1; m < 64; m <<= 1) v += __shfl_xor(v, m, 64);
  float rstd = rsqrtf(v * (1.f / 128.f) + 1e-5f);
  size_t hb = (size_t)node * 160;
  hcatH[hb + lane] = f2bf(d0 * rstd * n1g[lane] + n1b[lane]);
  hcatH[hb + 64 + lane] = f2bf(d1 * rstd * n1g[64 + lane] + n1b[64 + lane]);
  float dg = deg[node];
  int col = lane & 31;
  float y = msum[(size_t)node * 32 + col] / dg;
  float sy = y;
#pragma unroll
  for (int m = 1; m < 32; m <<= 1) sy += __shfl_xor(sy, m, 32);
  float mu2 = sy * (1.f / 32.f);
  float dy = y - mu2;
  float vy = dy * dy;
#pragma unroll
  for (int m = 1; m < 32; m <<= 1) vy += __shfl_xor(vy, m, 32);
  float rstd2 = rsqrtf(vy * (1.f / 32.f) + 1e-5f);
  if (lane < 32) hcatH[hb + 128 + col] = f2bf(dy * rstd2 * eng[col] + enb[col]);
}

// -------------------------------- node residual + final LN (+bf16 slice)
__global__ __launch_bounds__(256) void k_node_resid(
    const float* __restrict__ t2, float* __restrict__ featsAll, int k,
    const float* __restrict__ n2g, const float* __restrict__ n2b,
    unsigned short* __restrict__ fH, int N) {
  int node = blockIdx.x * 4 + (threadIdx.x >> 6);
  int lane = threadIdx.x & 63;
  if (node >= N) return;
  const float* tr = t2 + (size_t)node * 128;
  float x0 = tr[lane], x1 = tr[64 + lane];
  float s = x0 + x1;
#pragma unroll
  for (int m = 1; m < 64; m <<= 1) s += __shfl_xor(s, m, 64);
  float mu = s * (1.f / 128.f);
  float d0 = x0 - mu, d1 = x1 - mu;
  float v = d0 * d0 + d1 * d1;
#pragma unroll
  for (int m = 1; m < 64; m <<= 1) v += __shfl_xor(v, m, 64);
  float rstd = rsqrtf(v * (1.f / 128.f) + 1e-5f);
  const float* fk = featsAll + (size_t)node * 768 + k * 128;
  size_t ob = (size_t)node * 768 + (k + 1) * 128;
  float o0 = fk[lane] + d0 * rstd * n2g[lane] + n2b[lane];
  float o1 = fk[64 + lane] + d1 * rstd * n2g[64 + lane] + n2b[64 + lane];
  featsAll[ob + lane] = o0;
  featsAll[ob + 64 + lane] = o1;
  fH[ob + lane] = f2bf(o0);
  fH[ob + 64 + lane] = f2bf(o1);
}

// ------------------------------------- graph pooling (batch sorted -> runs)
__global__ __launch_bounds__(256) void k_pool2(const float* __restrict__ f,
                                               const int* __restrict__ batch,
                                               float* __restrict__ gsum,
                                               float* __restrict__ gcnt, int N) {
  int n0 = blockIdx.x * 64;
  int col = threadIdx.x;
  float acc = 0.f;
  int cur = -1;
  for (int i = 0; i < 64; ++i) {
    int n = n0 + i;
    if (n >= N) break;
    int b = batch[n];
    if (b != cur) {
      if (cur >= 0) atomicAdd(&gsum[cur * 256 + col], acc);
      acc = 0.f;
      cur = b;
    }
    acc += f[(size_t)n * 256 + col];
  }
  if (cur >= 0) atomicAdd(&gsum[cur * 256 + col], acc);
  if (threadIdx.x == 0) {
    int cnt = 0;
    cur = -1;
    for (int i = 0; i < 64; ++i) {
      int n = n0 + i;
      if (n >= N) break;
      int b = batch[n];
      if (b != cur) {
        if (cur >= 0) atomicAdd(&gcnt[cur], (float)cnt);
        cnt = 0;
        cur = b;
      }
      cnt++;
    }
    if (cur >= 0) atomicAdd(&gcnt[cur], (float)cnt);
  }
}

__global__ void k_gdiv(float* gsum, const float* gcnt, unsigned short* gH) {
  int b = blockIdx.x, j = threadIdx.x;
  float v = gsum[b * 256 + j] / fmaxf(gcnt[b], 1.f);
  gH[b * 256 + j] = f2bf(v);
}

__global__ void k_gout(const float* __restrict__ g2, const float* __restrict__ gW2,
                       const float* __restrict__ gb2, float* __restrict__ out) {
  int b = threadIdx.x;
  if (b >= 64) return;
  float s = gb2[0];
  for (int j = 0; j < 256; ++j) s += g2[b * 256 + j] * gW2[j];
  out[b] = s;
}

// ------------------------------------------------------------------- launch
extern "C" void kernel_launch(void* const* d_in, const int* in_sizes, int n_in,
                              void* d_out, int out_size, void* d_ws, size_t ws_size,
                              hipStream_t stream) {
  const float* coords = (const float*)d_in[0];
  const int* atomids = (const int*)d_in[1];
  const int* ei = (const int*)d_in[2];
  const int* batch = (const int*)d_in[3];
  const float* emb = (const float*)d_in[5];
  const float* keW1 = (const float*)d_in[6];
  const float* keb1 = (const float*)d_in[7];
  const float* keW2 = (const float*)d_in[8];
  const float* keb2 = (const float*)d_in[9];
  const float* keng = (const float*)d_in[10];
  const float* kenb = (const float*)d_in[11];
  const float* kn1g = (const float*)d_in[12];
  const float* kn1b = (const float*)d_in[13];
  const float* knW1 = (const float*)d_in[14];
  const float* knb1 = (const float*)d_in[15];
  const float* knW2 = (const float*)d_in[16];
  const float* knb2 = (const float*)d_in[17];
  const float* kn2g = (const float*)d_in[18];
  const float* kn2b = (const float*)d_in[19];
  const float* fW0 = (const float*)d_in[20];
  const float* fb0 = (const float*)d_in[21];
  const float* fW1 = (const float*)d_in[22];
  const float* fb1 = (const float*)d_in[23];
  const float* fW2 = (const float*)d_in[24];
  const float* fb2 = (const float*)d_in[25];
  const float* gW0 = (const float*)d_in[26];
  const float* gb0 = (const float*)d_in[27];
  const float* gW1 = (const float*)d_in[28];
  const float* gb1 = (const float*)d_in[29];
  const float* gW2 = (const float*)d_in[30];
  const float* gb2 = (const float*)d_in[31];

  const int N = in_sizes[0] / 3;
  const int E = in_sizes[2] / 2;
  const int planeN = N * 64;

  size_t off = 0;
  auto alloc = [&](size_t n) {
    float* p = (float*)d_ws + off;
    off += (n + 63) & ~(size_t)63;
    return p;
  };
  float* feats_all = alloc((size_t)N * 768);
  float* d_arr = alloc(E);
  float* degf = alloc(N);
  float* msum = alloc((size_t)N * 32);
  float* t2 = alloc((size_t)N * 128);
  float* f1 = alloc((size_t)N * 256);
  float* gsum = alloc(64 * 256);
  float* gcnt = alloc(64);
  float* g2 = alloc(64 * 256);
  int* cnt = (int*)alloc(N);
  int* cursor = (int*)alloc(N);
  int* ssrc = (int*)alloc(E);
  int* sdst = (int*)alloc(E);
  float* sd = alloc(E);

  unsigned short* ubase = (unsigned short*)(alloc(0));
  size_t uoff = 0;
  auto ualloc = [&](size_t n) {
    unsigned short* p = ubase + uoff;
    uoff += (n + 63) & ~(size_t)63;
    return p;
  };
  unsigned short* fH = ualloc((size_t)N * 768);
  unsigned short* ApU = ualloc((size_t)11 * planeN);
  unsigned short* BpU = ualloc((size_t)11 * planeN);
  unsigned short* hcatH = ualloc((size_t)N * 160);
  unsigned short* t1H = ualloc((size_t)N * 256);
  unsigned short* fAH = ualloc((size_t)N * 256);
  unsigned short* fBH = ualloc((size_t)N * 256);
  unsigned short* gH = ualloc(64 * 256);
  unsigned short* g1H = ualloc(64 * 256);
  const size_t sDst_ = 704 * 128, sSrc_ = 704 * 128, sEa_ = 704 * 64;
  const size_t sW2_ = 32 * 704, sN1_ = 256 * 160, sN2_ = 128 * 256;
  unsigned short* PdstH = ualloc(5 * sDst_); unsigned short* PdstL = ualloc(5 * sDst_);
  unsigned short* PsrcH = ualloc(5 * sSrc_); unsigned short* PsrcL = ualloc(5 * sSrc_);
  unsigned short* PeaH = ualloc(5 * sEa_);   unsigned short* PeaL = ualloc(5 * sEa_);
  unsigned short* PW2H = ualloc(5 * sW2_);   unsigned short* PW2L = ualloc(5 * sW2_);
  unsigned short* Pn1H = ualloc(5 * sN1_);   unsigned short* Pn1L = ualloc(5 * sN1_);
  unsigned short* Pn2H = ualloc(5 * sN2_);   unsigned short* Pn2L = ualloc(5 * sN2_);
  unsigned short* Pf0H = ualloc(256 * 768);  unsigned short* Pf0L = ualloc(256 * 768);
  unsigned short* Pf1H = ualloc(256 * 256);  unsigned short* Pf1L = ualloc(256 * 256);
  unsigned short* Pf2H = ualloc(256 * 256);  unsigned short* Pf2L = ualloc(256 * 256);
  unsigned short* Pg0H = ualloc(256 * 256);  unsigned short* Pg0L = ualloc(256 * 256);
  unsigned short* Pg1H = ualloc(256 * 256);  unsigned short* Pg1L = ualloc(256 * 256);

  auto pp = [&](const float* W, size_t wStr, int ldw, int K, int Kpad, int Nc, int Npad,
                unsigned short* hi, unsigned short* lo, size_t oStr, int layers) {
    int total = Npad * Kpad;
    k_prepack<<<dim3((total + 255) / 256, layers), 256, 0, stream>>>(
        W, wStr, ldw, K, Kpad, Nc, Npad, hi, lo, oStr);
  };
  pp(keW1, (size_t)321 * 642, 642, 128, 128, 642, 704, PdstH, PdstL, sDst_, 5);
  pp(keW1 + 128 * 642, (size_t)321 * 642, 642, 128, 128, 642, 704, PsrcH, PsrcL, sSrc_, 5);
  pp(keW1 + 256 * 642, (size_t)321 * 642, 642, 64, 64, 642, 704, PeaH, PeaL, sEa_, 5);
  pp(keW2, (size_t)642 * 32, 32, 642, 704, 32, 32, PW2H, PW2L, sW2_, 5);
  pp(knW1, (size_t)160 * 256, 256, 160, 160, 256, 256, Pn1H, Pn1L, sN1_, 5);
  pp(knW2, (size_t)256 * 128, 128, 256, 256, 128, 128, Pn2H, Pn2L, sN2_, 5);
  pp(fW0, 0, 256, 768, 768, 256, 256, Pf0H, Pf0L, 0, 1);
  pp(fW1, 0, 256, 256, 256, 256, 256, Pf1H, Pf1L, 0, 1);
  pp(fW2, 0, 256, 256, 256, 256, 256, Pf2H, Pf2L, 0, 1);
  pp(gW0, 0, 256, 256, 256, 256, 256, Pg0H, Pg0L, 0, 1);
  pp(gW1, 0, 256, 256, 256, 256, 256, Pg1H, Pg1L, 0, 1);

  // ---- node feats + edge sort by dst (counting sort)
  k_gather<<<(N * 128 + 255) / 256, 256, 0, stream>>>(atomids, emb, feats_all, fH, N);
  hipMemsetAsync(cnt, 0, (size_t)N * sizeof(int), stream);
  k_edge_prep<<<(E + 255) / 256, 256, 0, stream>>>(coords, ei, E, d_arr, cnt);
  k_scan<<<1, 1024, 0, stream>>>(cnt, N, cursor, degf);
  k_scatter<<<(E + 255) / 256, 256, 0, stream>>>(ei, E, d_arr, cursor, ssrc, sdst, sd);

  const int MT = (N + 127) / 128;
  for (int k = 0; k < 5; ++k) {
    gemm_bf<<<dim3(MT, 11), 256, 0, stream>>>(
        fH + k * 128, 768, PdstH + k * sDst_, PdstL + k * sDst_, 128,
        keb1 + k * 642, nullptr, 0, ApU, 0, planeN, N, 642, 128, 0, 0);
    gemm_bf<<<dim3(MT, 11), 256, 0, stream>>>(
        fH + k * 128, 768, PsrcH + k * sSrc_, PsrcL + k * sSrc_, 128,
        nullptr, nullptr, 0, BpU, 0, planeN, N, 642, 128, 0, 0);
    hipMemsetAsync(msum, 0, (size_t)N * 32 * sizeof(float), stream);
    k_edge_mfma<<<(E + 63) / 64, 256, 0, stream>>>(
        ApU, BpU, planeN, ssrc, sdst, sd, E,
        PeaH + k * sEa_,
        keW1 + (size_t)k * 321 * 642 + (size_t)320 * 642,
        PW2H + k * sW2_,
        keb2 + k * 32, keng + k * 32, kenb + k * 32, msum);
    k_node_ln<<<(N + 3) / 4, 256, 0, stream>>>(
        msum, degf, feats_all, k, kn1g + k * 128, kn1b + k * 128,
        keng + k * 32, kenb + k * 32, hcatH, N);
    gemm_bf<<<dim3(MT, 4), 256, 0, stream>>>(
        hcatH, 160, Pn1H + k * sN1_, Pn1L + k * sN1_, 160,
        knb1 + k * 256, nullptr, 0, t1H, 256, 0, N, 256, 160, 1, 0);
    gemm_bf<<<dim3(MT, 2), 256, 0, stream>>>(
        t1H, 256, Pn2H + k * sN2_, Pn2L + k * sN2_, 256,
        knb2 + k * 128, t2, 128, nullptr, 0, 0, N, 128, 256, 0, 0);
    k_node_resid<<<(N + 3) / 4, 256, 0, stream>>>(
        t2, feats_all, k, kn2g + k * 128, kn2b + k * 128, fH, N);
  }

  gemm_bf<<<dim3(MT, 4), 256, 0, stream>>>(
      fH, 768, Pf0H, Pf0L, 768, fb0, nullptr, 0, fAH, 256, 0, N, 256, 768, 1, 1);
  gemm_bf<<<dim3(MT, 4), 256, 0, stream>>>(
      fAH, 256, Pf1H, Pf1L, 256, fb1, nullptr, 0, fBH, 256, 0, N, 256, 256, 1, 0);
  gemm_bf<<<dim3(MT, 4), 256, 0, stream>>>(
      fBH, 256, Pf2H, Pf2L, 256, fb2, f1, 256, nullptr, 0, 0, N, 256, 256, 1, 0);

  hipMemsetAsync(gsum, 0, 64 * 256 * sizeof(float), stream);
  hipMemsetAsync(gcnt, 0, 64 * sizeof(float), stream);
  k_pool2<<<(N + 63) / 64, 256, 0, stream>>>(f1, batch, gsum, gcnt, N);
  k_gdiv<<<64, 256, 0, stream>>>(gsum, gcnt, gH);
  gemm_bf<<<dim3(1, 4), 256, 0, stream>>>(
      gH, 256, Pg0H, Pg0L, 256, gb0, nullptr, 0, g1H, 256, 0, 64, 256, 256, 1, 0);
  gemm_bf<<<dim3(1, 4), 256, 0, stream>>>(
      g1H, 256, Pg1H, Pg1L, 256, gb1, g2, 256, nullptr, 0, 0, 64, 256, 256, 1, 0);
  k_gout<<<1, 64, 0, stream>>>(g2, gW2, gb2, (float*)d_out);
}